// Round 1
// baseline (421.841 us; speedup 1.0000x reference)
//
#include <hip/hip_runtime.h>
#include <hip/hip_bf16.h>
#include <cstdint>

typedef __attribute__((ext_vector_type(8))) short short8;
typedef __attribute__((ext_vector_type(4))) float f32x4;

__device__ __forceinline__ uint16_t f2b(float f) {
  uint32_t u = __builtin_bit_cast(uint32_t, f);
  return (uint16_t)((u + 0x7FFFu + ((u >> 16) & 1u)) >> 16);
}
__device__ __forceinline__ float b2f(uint16_t h) {
  uint32_t u = ((uint32_t)h) << 16;
  return __builtin_bit_cast(float, u);
}
// async global->LDS, 16B per lane. LDS dest must be wave-uniform base + lane*16.
__device__ __forceinline__ void async16(void* lds, const void* g) {
  __builtin_amdgcn_global_load_lds(
      (const __attribute__((address_space(1))) uint32_t*)g,
      (__attribute__((address_space(3))) uint32_t*)lds, 16, 0, 0);
}

// ---------------- weight transpose + cast: w[K][N] f32 -> wT[N][K] bf16 ----
__global__ __launch_bounds__(256) void k_transpose_cast(
    const float* __restrict__ w, uint16_t* __restrict__ wT, int K, int N) {
  __shared__ float tile[64][65];
  const int tx = threadIdx.x;
  const int k0 = blockIdx.y * 64, n0 = blockIdx.x * 64;
  const int cr = tx & 15, rbase = tx >> 4;
#pragma unroll
  for (int rr = 0; rr < 4; ++rr) {
    int k = rbase + rr * 16;
    int n = cr * 4;
    float4 v = *(const float4*)&w[(size_t)(k0 + k) * N + (n0 + n)];
    tile[k][n + 0] = v.x; tile[k][n + 1] = v.y;
    tile[k][n + 2] = v.z; tile[k][n + 3] = v.w;
  }
  __syncthreads();
#pragma unroll
  for (int rr = 0; rr < 4; ++rr) {
    int n = rbase + rr * 16;
    int k = cr * 4;
    ushort4 o;
    o.x = f2b(tile[k + 0][n]);
    o.y = f2b(tile[k + 1][n]);
    o.z = f2b(tile[k + 2][n]);
    o.w = f2b(tile[k + 3][n]);
    *(ushort4*)&wT[(size_t)(n0 + n) * K + (k0 + k)] = o;
  }
}

// ---------------- layernorm: one wave per row of 1024, f32 in -> bf16 out --
__global__ __launch_bounds__(256) void k_layernorm(
    const float* __restrict__ x, const float* __restrict__ g,
    const float* __restrict__ b, uint16_t* __restrict__ out) {
  const int row = blockIdx.x * 4 + (threadIdx.x >> 6);
  const int lane = threadIdx.x & 63;
  const float* xr = x + (size_t)row * 1024;
  float4 v[4];
  float s = 0.f, ss = 0.f;
#pragma unroll
  for (int i = 0; i < 4; ++i) {
    v[i] = *(const float4*)&xr[i * 256 + lane * 4];
    s += v[i].x + v[i].y + v[i].z + v[i].w;
    ss += v[i].x * v[i].x + v[i].y * v[i].y + v[i].z * v[i].z + v[i].w * v[i].w;
  }
#pragma unroll
  for (int off = 1; off < 64; off <<= 1) {
    s += __shfl_xor(s, off);
    ss += __shfl_xor(ss, off);
  }
  float mu = s * (1.f / 1024.f);
  float rstd = rsqrtf(ss * (1.f / 1024.f) - mu * mu + 1e-5f);
#pragma unroll
  for (int i = 0; i < 4; ++i) {
    int col = i * 256 + lane * 4;
    float4 gv = *(const float4*)&g[col];
    float4 bv = *(const float4*)&b[col];
    ushort4 o;
    o.x = f2b((v[i].x - mu) * rstd * gv.x + bv.x);
    o.y = f2b((v[i].y - mu) * rstd * gv.y + bv.y);
    o.z = f2b((v[i].z - mu) * rstd * gv.z + bv.z);
    o.w = f2b((v[i].w - mu) * rstd * gv.w + bv.w);
    *(ushort4*)&out[(size_t)row * 1024 + col] = o;
  }
}

// ---------------- GEMM: C[M,N] = A[M,K](bf16) @ Bt[N,K](bf16)^T + bias -----
// EPI 0: bf16 out. EPI 1: f32 out + residual. EPI 2: bf16 out, exact GELU.
template <int EPI>
__global__ __launch_bounds__(256) void k_gemm(
    const uint16_t* __restrict__ A, const uint16_t* __restrict__ Bt,
    const float* __restrict__ bias, const float* __restrict__ resid,
    void* __restrict__ Cout, int M, int N, int K) {
  __shared__ __align__(16) uint16_t Alds[128 * 64];
  __shared__ __align__(16) uint16_t Blds[128 * 64];
  const int tid = threadIdx.x;
  const int lane = tid & 63;
  const int w = tid >> 6;
  const int wr = w >> 1, wc = w & 1;
  const int m0 = blockIdx.y * 128, n0 = blockIdx.x * 128;
  const int l15 = lane & 15, l4 = lane >> 4;
  f32x4 acc[4][4] = {};
  for (int k0 = 0; k0 < K; k0 += 64) {
#pragma unroll
    for (int c = 0; c < 4; ++c) {
      int i = c * 256 + tid;
      int row = i >> 3, d = (i & 7) * 8;
      async16(&Alds[i * 8], &A[(size_t)(m0 + row) * K + k0 + d]);
    }
#pragma unroll
    for (int c = 0; c < 4; ++c) {
      int i = c * 256 + tid;
      int row = i >> 3, d = (i & 7) * 8;
      async16(&Blds[i * 8], &Bt[(size_t)(n0 + row) * K + k0 + d]);
    }
    __syncthreads();
#pragma unroll
    for (int kc = 0; kc < 2; ++kc) {
      short8 af[4], bf[4];
#pragma unroll
      for (int m = 0; m < 4; ++m)
        af[m] = *(const short8*)&Alds[(wr * 64 + m * 16 + l15) * 64 + kc * 32 + l4 * 8];
#pragma unroll
      for (int n = 0; n < 4; ++n)
        bf[n] = *(const short8*)&Blds[(wc * 64 + n * 16 + l15) * 64 + kc * 32 + l4 * 8];
#pragma unroll
      for (int m = 0; m < 4; ++m)
#pragma unroll
        for (int n = 0; n < 4; ++n)
          acc[m][n] = __builtin_amdgcn_mfma_f32_16x16x32_bf16(af[m], bf[n], acc[m][n], 0, 0, 0);
    }
    __syncthreads();
  }
#pragma unroll
  for (int m = 0; m < 4; ++m) {
#pragma unroll
    for (int n = 0; n < 4; ++n) {
      int col = n0 + wc * 64 + n * 16 + l15;
      int rowb = m0 + wr * 64 + m * 16 + l4 * 4;
      float bv = bias[col];
#pragma unroll
      for (int r = 0; r < 4; ++r) {
        float val = acc[m][n][r] + bv;
        size_t idx = (size_t)(rowb + r) * N + col;
        if constexpr (EPI == 1) {
          ((float*)Cout)[idx] = val + resid[idx];
        } else if constexpr (EPI == 2) {
          float gl = 0.5f * val * (1.0f + erff(val * 0.70710678118654752f));
          ((uint16_t*)Cout)[idx] = f2b(gl);
        } else {
          ((uint16_t*)Cout)[idx] = f2b(val);
        }
      }
    }
  }
}

// ---------------- V transpose: qkv V-slice -> vT[bh][d=64][tok=2048] -------
__global__ __launch_bounds__(256) void k_vtrans(
    const uint16_t* __restrict__ qkv, uint16_t* __restrict__ vT) {
  __shared__ uint16_t tile[64][65];
  const int bh = blockIdx.y, t0 = blockIdx.x * 64;
  const int b = bh >> 4, h = bh & 15;
  const int tid = threadIdx.x;
#pragma unroll
  for (int c = 0; c < 2; ++c) {
    int i = c * 256 + tid;
    int tok = i >> 3, d0 = (i & 7) * 8;
    short8 v = *(const short8*)&qkv[((size_t)b * 2048 + t0 + tok) * 3072 + 2048 + h * 64 + d0];
#pragma unroll
    for (int j = 0; j < 8; ++j) tile[d0 + j][tok] = (uint16_t)v[j];
  }
  __syncthreads();
#pragma unroll
  for (int c = 0; c < 2; ++c) {
    int i = c * 256 + tid;
    int d = i >> 3, tk = (i & 7) * 8;
    short8 o;
#pragma unroll
    for (int j = 0; j < 8; ++j) o[j] = (short)tile[d][tk + j];
    *(short8*)&vT[((size_t)bh * 64 + d) * 2048 + t0 + tk] = o;
  }
}

// ---------------- flash attention: 4 waves x 16 q-rows, KBLK=64 ------------
__global__ __launch_bounds__(256) void k_attn(
    const uint16_t* __restrict__ qkv, const uint16_t* __restrict__ vT,
    uint16_t* __restrict__ ctx) {
  __shared__ __align__(16) uint16_t Klds[64 * 64];
  __shared__ __align__(16) uint16_t Vlds[64 * 64];
  __shared__ __align__(16) uint16_t Plds[4][16 * 64];
  const int bh = blockIdx.y, qt = blockIdx.x;
  const int b = bh >> 4, h = bh & 15;
  const int tid = threadIdx.x, lane = tid & 63, w = tid >> 6;
  const int l15 = lane & 15, l4 = lane >> 4;
  const size_t tokbase = (size_t)b * 2048;

  // Q A-fragments, scaled by 1/sqrt(64)=0.125 (exact, power of two)
  short8 qa[2];
  const int qrow = qt * 64 + w * 16 + l15;
#pragma unroll
  for (int kc = 0; kc < 2; ++kc) {
    short8 v = *(const short8*)&qkv[(tokbase + qrow) * 3072 + h * 64 + kc * 32 + l4 * 8];
#pragma unroll
    for (int j = 0; j < 8; ++j) v[j] = (short)f2b(b2f((uint16_t)v[j]) * 0.125f);
    qa[kc] = v;
  }

  float m_r[4], l_r[4];
  f32x4 o[4] = {};
#pragma unroll
  for (int r = 0; r < 4; ++r) { m_r[r] = -1e30f; l_r[r] = 0.f; }

  for (int t0 = 0; t0 < 2048; t0 += 64) {
#pragma unroll
    for (int c = 0; c < 2; ++c) {
      int i = c * 256 + tid;
      int row = i >> 3, d0 = (i & 7) * 8;
      async16(&Klds[i * 8], &qkv[(tokbase + t0 + row) * 3072 + 1024 + h * 64 + d0]);
    }
#pragma unroll
    for (int c = 0; c < 2; ++c) {
      int i = c * 256 + tid;
      int row = i >> 3, tk = (i & 7) * 8;
      async16(&Vlds[i * 8], &vT[((size_t)bh * 64 + row) * 2048 + t0 + tk]);
    }
    __syncthreads();

    // S = Q @ K^T  (rows: q, cols: 64 keys as 4 col-frags)
    f32x4 s[4] = {};
#pragma unroll
    for (int kc = 0; kc < 2; ++kc) {
#pragma unroll
      for (int c = 0; c < 4; ++c) {
        short8 kf = *(const short8*)&Klds[(c * 16 + l15) * 64 + kc * 32 + l4 * 8];
        s[c] = __builtin_amdgcn_mfma_f32_16x16x32_bf16(qa[kc], kf, s[c], 0, 0, 0);
      }
    }

    // online softmax (per q-row state replicated across the 16-lane group)
    float p[4][4];
    float scale_r[4];
#pragma unroll
    for (int r = 0; r < 4; ++r) {
      float pm = fmaxf(fmaxf(s[0][r], s[1][r]), fmaxf(s[2][r], s[3][r]));
#pragma unroll
      for (int off = 1; off < 16; off <<= 1) pm = fmaxf(pm, __shfl_xor(pm, off));
      float mn = fmaxf(m_r[r], pm);
      scale_r[r] = __expf(m_r[r] - mn);
      m_r[r] = mn;
      float ps = 0.f;
#pragma unroll
      for (int c = 0; c < 4; ++c) {
        float pv = __expf(s[c][r] - mn);
        p[c][r] = pv;
        ps += pv;
      }
#pragma unroll
      for (int off = 1; off < 16; off <<= 1) ps += __shfl_xor(ps, off);
      l_r[r] = l_r[r] * scale_r[r] + ps;
    }
#pragma unroll
    for (int df = 0; df < 4; ++df)
#pragma unroll
      for (int r = 0; r < 4; ++r) o[df][r] *= scale_r[r];

    // P (D-layout) -> LDS -> A-layout fragments, bf16
#pragma unroll
    for (int c = 0; c < 4; ++c)
#pragma unroll
      for (int r = 0; r < 4; ++r)
        Plds[w][(l4 * 4 + r) * 64 + c * 16 + l15] = f2b(p[c][r]);

    // O += P @ V
#pragma unroll
    for (int kc = 0; kc < 2; ++kc) {
      short8 pa = *(const short8*)&Plds[w][l15 * 64 + kc * 32 + l4 * 8];
#pragma unroll
      for (int df = 0; df < 4; ++df) {
        short8 vf = *(const short8*)&Vlds[(df * 16 + l15) * 64 + kc * 32 + l4 * 8];
        o[df] = __builtin_amdgcn_mfma_f32_16x16x32_bf16(pa, vf, o[df], 0, 0, 0);
      }
    }
    __syncthreads();
  }

#pragma unroll
  for (int df = 0; df < 4; ++df) {
#pragma unroll
    for (int r = 0; r < 4; ++r) {
      float val = o[df][r] / l_r[r];
      int tok = qt * 64 + w * 16 + l4 * 4 + r;
      ctx[(tokbase + tok) * 1024 + h * 64 + df * 16 + l15] = f2b(val);
    }
  }
}

// ---------------------------------------------------------------------------
extern "C" void kernel_launch(void* const* d_in, const int* in_sizes, int n_in,
                              void* d_out, int out_size, void* d_ws, size_t ws_size,
                              hipStream_t stream) {
  const float* x      = (const float*)d_in[0];
  const float* ln1_g  = (const float*)d_in[1];
  const float* ln1_b  = (const float*)d_in[2];
  const float* ln2_g  = (const float*)d_in[3];
  const float* ln2_b  = (const float*)d_in[4];
  const float* w_qkv  = (const float*)d_in[5];
  const float* b_qkv  = (const float*)d_in[6];
  const float* w_proj = (const float*)d_in[7];
  const float* b_proj = (const float*)d_in[8];
  const float* w_fc1  = (const float*)d_in[9];
  const float* b_fc1  = (const float*)d_in[10];
  const float* w_fc2  = (const float*)d_in[11];
  const float* b_fc2  = (const float*)d_in[12];
  float* out = (float*)d_out;
  char* ws = (char*)d_ws;

  // workspace layout (bytes); act aliases qkv+vT (both dead by FC1)
  uint16_t* wTqkv  = (uint16_t*)(ws + 0);         //  6 MB  [3072][1024]
  uint16_t* wTproj = (uint16_t*)(ws + 6291456);   //  2 MB  [1024][1024]
  uint16_t* wTfc1  = (uint16_t*)(ws + 8388608);   //  8 MB  [4096][1024]
  uint16_t* wTfc2  = (uint16_t*)(ws + 16777216);  //  8 MB  [1024][4096]
  uint16_t* hbuf   = (uint16_t*)(ws + 25165824);  //  8 MB  [4096][1024] (h1 then h2)
  uint16_t* qkvb   = (uint16_t*)(ws + 33554432);  // 24 MB  [4096][3072]
  uint16_t* vTb    = (uint16_t*)(ws + 58720256);  //  8 MB  [32][64][2048]
  uint16_t* ctxb   = (uint16_t*)(ws + 67108864);  //  8 MB  [4096][1024]
  float*    x2b    = (float*)   (ws + 75497472);  // 16 MB  [4096][1024]
  uint16_t* actb   = (uint16_t*)(ws + 33554432);  // 32 MB  [4096][4096]

  k_transpose_cast<<<dim3(3072 / 64, 1024 / 64), 256, 0, stream>>>(w_qkv, wTqkv, 1024, 3072);
  k_transpose_cast<<<dim3(1024 / 64, 1024 / 64), 256, 0, stream>>>(w_proj, wTproj, 1024, 1024);
  k_transpose_cast<<<dim3(4096 / 64, 1024 / 64), 256, 0, stream>>>(w_fc1, wTfc1, 1024, 4096);
  k_transpose_cast<<<dim3(1024 / 64, 4096 / 64), 256, 0, stream>>>(w_fc2, wTfc2, 4096, 1024);

  k_layernorm<<<1024, 256, 0, stream>>>(x, ln1_g, ln1_b, hbuf);
  k_gemm<0><<<dim3(24, 32), 256, 0, stream>>>(hbuf, wTqkv, b_qkv, nullptr, qkvb, 4096, 3072, 1024);
  k_vtrans<<<dim3(32, 32), 256, 0, stream>>>(qkvb, vTb);
  k_attn<<<dim3(32, 32), 256, 0, stream>>>(qkvb, vTb, ctxb);
  k_gemm<1><<<dim3(8, 32), 256, 0, stream>>>(ctxb, wTproj, b_proj, x, x2b, 4096, 1024, 1024);
  k_layernorm<<<1024, 256, 0, stream>>>(x2b, ln2_g, ln2_b, hbuf);
  k_gemm<2><<<dim3(32, 32), 256, 0, stream>>>(hbuf, wTfc1, b_fc1, nullptr, actb, 4096, 4096, 1024);
  k_gemm<1><<<dim3(8, 32), 256, 0, stream>>>(actb, wTfc2, b_fc2, x2b, out, 4096, 1024, 4096);
}

// Round 2
// 413.139 us; speedup vs baseline: 1.0211x; 1.0211x over previous
//
#include <hip/hip_runtime.h>
#include <hip/hip_bf16.h>
#include <cstdint>

typedef __attribute__((ext_vector_type(8))) short short8;
typedef __attribute__((ext_vector_type(4))) float f32x4;

__device__ __forceinline__ uint16_t f2b(float f) {
  uint32_t u = __builtin_bit_cast(uint32_t, f);
  return (uint16_t)((u + 0x7FFFu + ((u >> 16) & 1u)) >> 16);
}
__device__ __forceinline__ float b2f(uint16_t h) {
  uint32_t u = ((uint32_t)h) << 16;
  return __builtin_bit_cast(float, u);
}
// async global->LDS, 16B per lane. LDS dest must be wave-uniform base + lane*16.
__device__ __forceinline__ void async16(void* lds, const void* g) {
  __builtin_amdgcn_global_load_lds(
      (const __attribute__((address_space(1))) uint32_t*)g,
      (__attribute__((address_space(3))) uint32_t*)lds, 16, 0, 0);
}

// ---------------- weight transpose + cast: w[K][N] f32 -> wT[N][K] bf16 ----
__global__ __launch_bounds__(256) void k_transpose_cast(
    const float* __restrict__ w, uint16_t* __restrict__ wT, int K, int N) {
  __shared__ float tile[64][65];
  const int tx = threadIdx.x;
  const int k0 = blockIdx.y * 64, n0 = blockIdx.x * 64;
  const int cr = tx & 15, rbase = tx >> 4;
#pragma unroll
  for (int rr = 0; rr < 4; ++rr) {
    int k = rbase + rr * 16;
    int n = cr * 4;
    float4 v = *(const float4*)&w[(size_t)(k0 + k) * N + (n0 + n)];
    tile[k][n + 0] = v.x; tile[k][n + 1] = v.y;
    tile[k][n + 2] = v.z; tile[k][n + 3] = v.w;
  }
  __syncthreads();
#pragma unroll
  for (int rr = 0; rr < 4; ++rr) {
    int n = rbase + rr * 16;
    int k = cr * 4;
    ushort4 o;
    o.x = f2b(tile[k + 0][n]);
    o.y = f2b(tile[k + 1][n]);
    o.z = f2b(tile[k + 2][n]);
    o.w = f2b(tile[k + 3][n]);
    *(ushort4*)&wT[(size_t)(n0 + n) * K + (k0 + k)] = o;
  }
}

// ---------------- layernorm: one wave per row of 1024, f32 in -> bf16 out --
__global__ __launch_bounds__(256) void k_layernorm(
    const float* __restrict__ x, const float* __restrict__ g,
    const float* __restrict__ b, uint16_t* __restrict__ out) {
  const int row = blockIdx.x * 4 + (threadIdx.x >> 6);
  const int lane = threadIdx.x & 63;
  const float* xr = x + (size_t)row * 1024;
  float4 v[4];
  float s = 0.f, ss = 0.f;
#pragma unroll
  for (int i = 0; i < 4; ++i) {
    v[i] = *(const float4*)&xr[i * 256 + lane * 4];
    s += v[i].x + v[i].y + v[i].z + v[i].w;
    ss += v[i].x * v[i].x + v[i].y * v[i].y + v[i].z * v[i].z + v[i].w * v[i].w;
  }
#pragma unroll
  for (int off = 1; off < 64; off <<= 1) {
    s += __shfl_xor(s, off);
    ss += __shfl_xor(ss, off);
  }
  float mu = s * (1.f / 1024.f);
  float rstd = rsqrtf(ss * (1.f / 1024.f) - mu * mu + 1e-5f);
#pragma unroll
  for (int i = 0; i < 4; ++i) {
    int col = i * 256 + lane * 4;
    float4 gv = *(const float4*)&g[col];
    float4 bv = *(const float4*)&b[col];
    ushort4 o;
    o.x = f2b((v[i].x - mu) * rstd * gv.x + bv.x);
    o.y = f2b((v[i].y - mu) * rstd * gv.y + bv.y);
    o.z = f2b((v[i].z - mu) * rstd * gv.z + bv.z);
    o.w = f2b((v[i].w - mu) * rstd * gv.w + bv.w);
    *(ushort4*)&out[(size_t)row * 1024 + col] = o;
  }
}

// ---------------- prefill: out = a + bias (row-broadcast), f32 -------------
__global__ __launch_bounds__(256) void k_prefill(
    const float* __restrict__ a, const float* __restrict__ bias,
    float* __restrict__ out, int N) {
  int i = (blockIdx.x * 256 + threadIdx.x) * 4;
  float4 v = *(const float4*)&a[i];
  float4 bv = *(const float4*)&bias[i & (N - 1)];
  v.x += bv.x; v.y += bv.y; v.z += bv.z; v.w += bv.w;
  *(float4*)&out[i] = v;
}

// ---------------- GEMM: C[M,N] = A[M,K](bf16) @ Bt[N,K](bf16)^T + bias -----
// EPI 0: bf16 out. EPI 2: bf16 out, exact GELU.
template <int EPI>
__global__ __launch_bounds__(256) void k_gemm(
    const uint16_t* __restrict__ A, const uint16_t* __restrict__ Bt,
    const float* __restrict__ bias, void* __restrict__ Cout,
    int M, int N, int K) {
  __shared__ __align__(16) uint16_t Alds[128 * 64];
  __shared__ __align__(16) uint16_t Blds[128 * 64];
  const int tid = threadIdx.x;
  const int lane = tid & 63;
  const int w = tid >> 6;
  const int wr = w >> 1, wc = w & 1;
  const int m0 = blockIdx.y * 128, n0 = blockIdx.x * 128;
  const int l15 = lane & 15, l4 = lane >> 4;
  f32x4 acc[4][4] = {};
  for (int k0 = 0; k0 < K; k0 += 64) {
#pragma unroll
    for (int c = 0; c < 4; ++c) {
      int i = c * 256 + tid;
      int row = i >> 3, d = (i & 7) * 8;
      async16(&Alds[i * 8], &A[(size_t)(m0 + row) * K + k0 + d]);
    }
#pragma unroll
    for (int c = 0; c < 4; ++c) {
      int i = c * 256 + tid;
      int row = i >> 3, d = (i & 7) * 8;
      async16(&Blds[i * 8], &Bt[(size_t)(n0 + row) * K + k0 + d]);
    }
    __syncthreads();
#pragma unroll
    for (int kc = 0; kc < 2; ++kc) {
      short8 af[4], bf[4];
#pragma unroll
      for (int m = 0; m < 4; ++m)
        af[m] = *(const short8*)&Alds[(wr * 64 + m * 16 + l15) * 64 + kc * 32 + l4 * 8];
#pragma unroll
      for (int n = 0; n < 4; ++n)
        bf[n] = *(const short8*)&Blds[(wc * 64 + n * 16 + l15) * 64 + kc * 32 + l4 * 8];
#pragma unroll
      for (int m = 0; m < 4; ++m)
#pragma unroll
        for (int n = 0; n < 4; ++n)
          acc[m][n] = __builtin_amdgcn_mfma_f32_16x16x32_bf16(af[m], bf[n], acc[m][n], 0, 0, 0);
    }
    __syncthreads();
  }
#pragma unroll
  for (int m = 0; m < 4; ++m) {
#pragma unroll
    for (int n = 0; n < 4; ++n) {
      int col = n0 + wc * 64 + n * 16 + l15;
      int rowb = m0 + wr * 64 + m * 16 + l4 * 4;
      float bv = bias[col];
#pragma unroll
      for (int r = 0; r < 4; ++r) {
        float val = acc[m][n][r] + bv;
        size_t idx = (size_t)(rowb + r) * N + col;
        if constexpr (EPI == 2) {
          float gl = 0.5f * val * (1.0f + erff(val * 0.70710678118654752f));
          ((uint16_t*)Cout)[idx] = f2b(gl);
        } else {
          ((uint16_t*)Cout)[idx] = f2b(val);
        }
      }
    }
  }
}

// ---------------- split-K GEMM: atomicAdd into prefilled f32 out -----------
__global__ __launch_bounds__(256) void k_gemm_splitk(
    const uint16_t* __restrict__ A, const uint16_t* __restrict__ Bt,
    float* __restrict__ out, int M, int N, int K, int Kc) {
  __shared__ __align__(16) uint16_t Alds[128 * 64];
  __shared__ __align__(16) uint16_t Blds[128 * 64];
  const int tid = threadIdx.x;
  const int lane = tid & 63;
  const int w = tid >> 6;
  const int wr = w >> 1, wc = w & 1;
  const int m0 = blockIdx.y * 128, n0 = blockIdx.x * 128;
  const int l15 = lane & 15, l4 = lane >> 4;
  const int kbeg = blockIdx.z * Kc, kend = kbeg + Kc;
  f32x4 acc[4][4] = {};
  for (int k0 = kbeg; k0 < kend; k0 += 64) {
#pragma unroll
    for (int c = 0; c < 4; ++c) {
      int i = c * 256 + tid;
      int row = i >> 3, d = (i & 7) * 8;
      async16(&Alds[i * 8], &A[(size_t)(m0 + row) * K + k0 + d]);
    }
#pragma unroll
    for (int c = 0; c < 4; ++c) {
      int i = c * 256 + tid;
      int row = i >> 3, d = (i & 7) * 8;
      async16(&Blds[i * 8], &Bt[(size_t)(n0 + row) * K + k0 + d]);
    }
    __syncthreads();
#pragma unroll
    for (int kc = 0; kc < 2; ++kc) {
      short8 af[4], bf[4];
#pragma unroll
      for (int m = 0; m < 4; ++m)
        af[m] = *(const short8*)&Alds[(wr * 64 + m * 16 + l15) * 64 + kc * 32 + l4 * 8];
#pragma unroll
      for (int n = 0; n < 4; ++n)
        bf[n] = *(const short8*)&Blds[(wc * 64 + n * 16 + l15) * 64 + kc * 32 + l4 * 8];
#pragma unroll
      for (int m = 0; m < 4; ++m)
#pragma unroll
        for (int n = 0; n < 4; ++n)
          acc[m][n] = __builtin_amdgcn_mfma_f32_16x16x32_bf16(af[m], bf[n], acc[m][n], 0, 0, 0);
    }
    __syncthreads();
  }
#pragma unroll
  for (int m = 0; m < 4; ++m) {
#pragma unroll
    for (int n = 0; n < 4; ++n) {
      int col = n0 + wc * 64 + n * 16 + l15;
      int rowb = m0 + wr * 64 + m * 16 + l4 * 4;
#pragma unroll
      for (int r = 0; r < 4; ++r)
        unsafeAtomicAdd(&out[(size_t)(rowb + r) * N + col], acc[m][n][r]);
    }
  }
}

// ---------------- V transpose: qkv V-slice -> vT[bh][d=64][tok=2048] -------
__global__ __launch_bounds__(256) void k_vtrans(
    const uint16_t* __restrict__ qkv, uint16_t* __restrict__ vT) {
  __shared__ uint16_t tile[64][65];
  const int bh = blockIdx.y, t0 = blockIdx.x * 64;
  const int b = bh >> 4, h = bh & 15;
  const int tid = threadIdx.x;
#pragma unroll
  for (int c = 0; c < 2; ++c) {
    int i = c * 256 + tid;
    int tok = i >> 3, d0 = (i & 7) * 8;
    short8 v = *(const short8*)&qkv[((size_t)b * 2048 + t0 + tok) * 3072 + 2048 + h * 64 + d0];
#pragma unroll
    for (int j = 0; j < 8; ++j) tile[d0 + j][tok] = (uint16_t)v[j];
  }
  __syncthreads();
#pragma unroll
  for (int c = 0; c < 2; ++c) {
    int i = c * 256 + tid;
    int d = i >> 3, tk = (i & 7) * 8;
    short8 o;
#pragma unroll
    for (int j = 0; j < 8; ++j) o[j] = (short)tile[d][tk + j];
    *(short8*)&vT[((size_t)bh * 64 + d) * 2048 + t0 + tk] = o;
  }
}

// ---------------- flash attention: 4 waves x 16 q-rows, KBLK=64 ------------
// K/V/P LDS tiles XOR-swizzled (elem col ^= (row&7)<<3); K/V staged via
// global_load_lds with pre-swizzled GLOBAL source (rule #21). K/V double-
// buffered; stage of tile t+1 issued before compute of tile t (minimal 2ph).
// Softmax in exp2 domain: Q pre-scaled by 0.125*log2e.
__global__ __launch_bounds__(256) void k_attn(
    const uint16_t* __restrict__ qkv, const uint16_t* __restrict__ vT,
    uint16_t* __restrict__ ctx) {
  __shared__ __align__(16) uint16_t Klds[2][64 * 64];
  __shared__ __align__(16) uint16_t Vlds[2][64 * 64];
  __shared__ __align__(16) uint16_t Plds[4][16 * 64];
  const int bh = blockIdx.y, qt = blockIdx.x;
  const int b = bh >> 4, h = bh & 15;
  const int tid = threadIdx.x, lane = tid & 63, w = tid >> 6;
  const int l15 = lane & 15, l4 = lane >> 4;
  const int sw = (l15 & 7) << 3;  // read-side swizzle for rows indexed by l15
  const size_t tokbase = (size_t)b * 2048;

  // Q A-fragments, scaled by 0.125 * log2(e) so softmax uses exp2
  short8 qa[2];
  const int qrow = qt * 64 + w * 16 + l15;
  const float QSC = 0.125f * 1.44269504088896340736f;
#pragma unroll
  for (int kc = 0; kc < 2; ++kc) {
    short8 v = *(const short8*)&qkv[(tokbase + qrow) * 3072 + h * 64 + kc * 32 + l4 * 8];
#pragma unroll
    for (int j = 0; j < 8; ++j) v[j] = (short)f2b(b2f((uint16_t)v[j]) * QSC);
    qa[kc] = v;
  }

  float m_r[4], l_r[4];
  f32x4 o[4] = {};
#pragma unroll
  for (int r = 0; r < 4; ++r) { m_r[r] = -1e30f; l_r[r] = 0.f; }

  auto stage = [&](int buf, int t0) {
#pragma unroll
    for (int c = 0; c < 2; ++c) {
      int i = c * 256 + tid;
      int row = i >> 3, colE = (i & 7) * 8;
      int colS = colE ^ ((row & 7) << 3);  // pre-swizzled global source
      async16(&Klds[buf][i * 8],
              &qkv[(tokbase + t0 + row) * 3072 + 1024 + h * 64 + colS]);
    }
#pragma unroll
    for (int c = 0; c < 2; ++c) {
      int i = c * 256 + tid;
      int row = i >> 3, tkE = (i & 7) * 8;
      int tkS = tkE ^ ((row & 7) << 3);
      async16(&Vlds[buf][i * 8],
              &vT[((size_t)bh * 64 + row) * 2048 + t0 + tkS]);
    }
  };

  stage(0, 0);
  __syncthreads();
  int cur = 0;

  for (int t0 = 0; t0 < 2048; t0 += 64) {
    if (t0 + 64 < 2048) stage(cur ^ 1, t0 + 64);

    // S = Q @ K^T (swizzled K reads)
    f32x4 s[4] = {};
#pragma unroll
    for (int kc = 0; kc < 2; ++kc) {
      const int cc = (kc * 32 + l4 * 8) ^ sw;
#pragma unroll
      for (int c = 0; c < 4; ++c) {
        short8 kf = *(const short8*)&Klds[cur][(c * 16 + l15) * 64 + cc];
        s[c] = __builtin_amdgcn_mfma_f32_16x16x32_bf16(qa[kc], kf, s[c], 0, 0, 0);
      }
    }

    // online softmax in exp2 domain (state per q-row, replicated over 16 lanes)
    float p[4][4];
    float scale_r[4];
#pragma unroll
    for (int r = 0; r < 4; ++r) {
      float pm = fmaxf(fmaxf(s[0][r], s[1][r]), fmaxf(s[2][r], s[3][r]));
#pragma unroll
      for (int off = 1; off < 16; off <<= 1) pm = fmaxf(pm, __shfl_xor(pm, off));
      float mn = fmaxf(m_r[r], pm);
      scale_r[r] = exp2f(m_r[r] - mn);
      m_r[r] = mn;
      float ps = 0.f;
#pragma unroll
      for (int c = 0; c < 4; ++c) {
        float pv = exp2f(s[c][r] - mn);
        p[c][r] = pv;
        ps += pv;
      }
#pragma unroll
      for (int off = 1; off < 16; off <<= 1) ps += __shfl_xor(ps, off);
      l_r[r] = l_r[r] * scale_r[r] + ps;
    }
#pragma unroll
    for (int df = 0; df < 4; ++df)
#pragma unroll
      for (int r = 0; r < 4; ++r) o[df][r] *= scale_r[r];

    // P (D-layout) -> LDS (swizzled) -> A-layout fragments, bf16
#pragma unroll
    for (int c = 0; c < 4; ++c)
#pragma unroll
      for (int r = 0; r < 4; ++r) {
        int row = l4 * 4 + r;
        Plds[w][row * 64 + ((c * 16 + l15) ^ ((row & 7) << 3))] = f2b(p[c][r]);
      }

    // O += P @ V (swizzled P/V reads)
#pragma unroll
    for (int kc = 0; kc < 2; ++kc) {
      const int cc = (kc * 32 + l4 * 8) ^ sw;
      short8 pa = *(const short8*)&Plds[w][l15 * 64 + cc];
#pragma unroll
      for (int df = 0; df < 4; ++df) {
        short8 vf = *(const short8*)&Vlds[cur][(df * 16 + l15) * 64 + cc];
        o[df] = __builtin_amdgcn_mfma_f32_16x16x32_bf16(pa, vf, o[df], 0, 0, 0);
      }
    }
    __syncthreads();
    cur ^= 1;
  }

#pragma unroll
  for (int df = 0; df < 4; ++df) {
#pragma unroll
    for (int r = 0; r < 4; ++r) {
      float val = o[df][r] / l_r[r];
      int tok = qt * 64 + w * 16 + l4 * 4 + r;
      ctx[(tokbase + tok) * 1024 + h * 64 + df * 16 + l15] = f2b(val);
    }
  }
}

// ---------------------------------------------------------------------------
extern "C" void kernel_launch(void* const* d_in, const int* in_sizes, int n_in,
                              void* d_out, int out_size, void* d_ws, size_t ws_size,
                              hipStream_t stream) {
  const float* x      = (const float*)d_in[0];
  const float* ln1_g  = (const float*)d_in[1];
  const float* ln1_b  = (const float*)d_in[2];
  const float* ln2_g  = (const float*)d_in[3];
  const float* ln2_b  = (const float*)d_in[4];
  const float* w_qkv  = (const float*)d_in[5];
  const float* b_qkv  = (const float*)d_in[6];
  const float* w_proj = (const float*)d_in[7];
  const float* b_proj = (const float*)d_in[8];
  const float* w_fc1  = (const float*)d_in[9];
  const float* b_fc1  = (const float*)d_in[10];
  const float* w_fc2  = (const float*)d_in[11];
  const float* b_fc2  = (const float*)d_in[12];
  float* out = (float*)d_out;
  char* ws = (char*)d_ws;

  // workspace layout (bytes); actb aliases qkvb+vTb (both dead by FC1)
  uint16_t* wTqkv  = (uint16_t*)(ws + 0);         //  6 MB  [3072][1024]
  uint16_t* wTproj = (uint16_t*)(ws + 6291456);   //  2 MB  [1024][1024]
  uint16_t* wTfc1  = (uint16_t*)(ws + 8388608);   //  8 MB  [4096][1024]
  uint16_t* wTfc2  = (uint16_t*)(ws + 16777216);  //  8 MB  [1024][4096]
  uint16_t* hbuf   = (uint16_t*)(ws + 25165824);  //  8 MB  [4096][1024] (h1 then h2)
  uint16_t* qkvb   = (uint16_t*)(ws + 33554432);  // 24 MB  [4096][3072]
  uint16_t* vTb    = (uint16_t*)(ws + 58720256);  //  8 MB  [32][64][2048]
  uint16_t* ctxb   = (uint16_t*)(ws + 67108864);  //  8 MB  [4096][1024]
  float*    x2b    = (float*)   (ws + 75497472);  // 16 MB  [4096][1024]
  uint16_t* actb   = (uint16_t*)(ws + 33554432);  // 32 MB  [4096][4096]

  k_transpose_cast<<<dim3(3072 / 64, 1024 / 64), 256, 0, stream>>>(w_qkv, wTqkv, 1024, 3072);
  k_transpose_cast<<<dim3(1024 / 64, 1024 / 64), 256, 0, stream>>>(w_proj, wTproj, 1024, 1024);
  k_transpose_cast<<<dim3(4096 / 64, 1024 / 64), 256, 0, stream>>>(w_fc1, wTfc1, 1024, 4096);
  k_transpose_cast<<<dim3(1024 / 64, 4096 / 64), 256, 0, stream>>>(w_fc2, wTfc2, 4096, 1024);

  k_layernorm<<<1024, 256, 0, stream>>>(x, ln1_g, ln1_b, hbuf);
  k_gemm<0><<<dim3(24, 32), 256, 0, stream>>>(hbuf, wTqkv, b_qkv, qkvb, 4096, 3072, 1024);
  k_vtrans<<<dim3(32, 32), 256, 0, stream>>>(qkvb, vTb);
  k_attn<<<dim3(32, 32), 256, 0, stream>>>(qkvb, vTb, ctxb);

  // proj: x2 = x + ctx @ w_proj + b_proj   (split-K=2, atomic accumulate)
  k_prefill<<<4096, 256, 0, stream>>>(x, b_proj, x2b, 1024);
  k_gemm_splitk<<<dim3(8, 32, 2), 256, 0, stream>>>(ctxb, wTproj, x2b, 4096, 1024, 1024, 512);

  k_layernorm<<<1024, 256, 0, stream>>>(x2b, ln2_g, ln2_b, hbuf);
  k_gemm<2><<<dim3(32, 32), 256, 0, stream>>>(hbuf, wTfc1, b_fc1, actb, 4096, 4096, 1024);

  // fc2: out = x2 + act @ w_fc2 + b_fc2   (split-K=4, atomic accumulate)
  k_prefill<<<4096, 256, 0, stream>>>(x2b, b_fc2, out, 1024);
  k_gemm_splitk<<<dim3(8, 32, 4), 256, 0, stream>>>(actb, wTfc2, out, 4096, 1024, 4096, 1024);
}

// Round 3
// 374.081 us; speedup vs baseline: 1.1277x; 1.1044x over previous
//
#include <hip/hip_runtime.h>
#include <hip/hip_bf16.h>
#include <cstdint>

typedef __attribute__((ext_vector_type(8))) short short8;
typedef __attribute__((ext_vector_type(4))) float f32x4;

__device__ __forceinline__ uint16_t f2b(float f) {
  uint32_t u = __builtin_bit_cast(uint32_t, f);
  return (uint16_t)((u + 0x7FFFu + ((u >> 16) & 1u)) >> 16);
}
__device__ __forceinline__ float b2f(uint16_t h) {
  uint32_t u = ((uint32_t)h) << 16;
  return __builtin_bit_cast(float, u);
}
// async global->LDS, 16B per lane. LDS dest must be wave-uniform base + lane*16.
__device__ __forceinline__ void async16(void* lds, const void* g) {
  __builtin_amdgcn_global_load_lds(
      (const __attribute__((address_space(1))) uint32_t*)g,
      (__attribute__((address_space(3))) uint32_t*)lds, 16, 0, 0);
}

// ---------------- weight transpose + cast: w[K][N] f32 -> wT[N][K] bf16 ----
__global__ __launch_bounds__(256) void k_transpose_cast(
    const float* __restrict__ w, uint16_t* __restrict__ wT, int K, int N) {
  __shared__ float tile[64][65];
  const int tx = threadIdx.x;
  const int k0 = blockIdx.y * 64, n0 = blockIdx.x * 64;
  const int cr = tx & 15, rbase = tx >> 4;
#pragma unroll
  for (int rr = 0; rr < 4; ++rr) {
    int k = rbase + rr * 16;
    int n = cr * 4;
    float4 v = *(const float4*)&w[(size_t)(k0 + k) * N + (n0 + n)];
    tile[k][n + 0] = v.x; tile[k][n + 1] = v.y;
    tile[k][n + 2] = v.z; tile[k][n + 3] = v.w;
  }
  __syncthreads();
#pragma unroll
  for (int rr = 0; rr < 4; ++rr) {
    int n = rbase + rr * 16;
    int k = cr * 4;
    ushort4 o;
    o.x = f2b(tile[k + 0][n]);
    o.y = f2b(tile[k + 1][n]);
    o.z = f2b(tile[k + 2][n]);
    o.w = f2b(tile[k + 3][n]);
    *(ushort4*)&wT[(size_t)(n0 + n) * K + (k0 + k)] = o;
  }
}

// ---------------- layernorm: one wave per row of 1024, f32 in -> bf16 out --
__global__ __launch_bounds__(256) void k_layernorm(
    const float* __restrict__ x, const float* __restrict__ g,
    const float* __restrict__ b, uint16_t* __restrict__ out) {
  const int row = blockIdx.x * 4 + (threadIdx.x >> 6);
  const int lane = threadIdx.x & 63;
  const float* xr = x + (size_t)row * 1024;
  float4 v[4];
  float s = 0.f, ss = 0.f;
#pragma unroll
  for (int i = 0; i < 4; ++i) {
    v[i] = *(const float4*)&xr[i * 256 + lane * 4];
    s += v[i].x + v[i].y + v[i].z + v[i].w;
    ss += v[i].x * v[i].x + v[i].y * v[i].y + v[i].z * v[i].z + v[i].w * v[i].w;
  }
#pragma unroll
  for (int off = 1; off < 64; off <<= 1) {
    s += __shfl_xor(s, off);
    ss += __shfl_xor(ss, off);
  }
  float mu = s * (1.f / 1024.f);
  float rstd = rsqrtf(ss * (1.f / 1024.f) - mu * mu + 1e-5f);
#pragma unroll
  for (int i = 0; i < 4; ++i) {
    int col = i * 256 + lane * 4;
    float4 gv = *(const float4*)&g[col];
    float4 bv = *(const float4*)&b[col];
    ushort4 o;
    o.x = f2b((v[i].x - mu) * rstd * gv.x + bv.x);
    o.y = f2b((v[i].y - mu) * rstd * gv.y + bv.y);
    o.z = f2b((v[i].z - mu) * rstd * gv.z + bv.z);
    o.w = f2b((v[i].w - mu) * rstd * gv.w + bv.w);
    *(ushort4*)&out[(size_t)row * 1024 + col] = o;
  }
}

// ---------------- prefill: out = a + bias (row-broadcast), f32 -------------
__global__ __launch_bounds__(256) void k_prefill(
    const float* __restrict__ a, const float* __restrict__ bias,
    float* __restrict__ out, int N) {
  int i = (blockIdx.x * 256 + threadIdx.x) * 4;
  float4 v = *(const float4*)&a[i];
  float4 bv = *(const float4*)&bias[i & (N - 1)];
  v.x += bv.x; v.y += bv.y; v.z += bv.z; v.w += bv.w;
  *(float4*)&out[i] = v;
}

// ---------------- GEMM: C[M,N] = A[M,K](bf16) @ Bt[N,K](bf16)^T + bias -----
// EPI 0: bf16 out. EPI 2: bf16 out, exact GELU.
// EPI 3: qkv special — cols<2048 -> bf16 C; cols>=2048 (V) -> transposed vT.
template <int EPI>
__global__ __launch_bounds__(256) void k_gemm(
    const uint16_t* __restrict__ A, const uint16_t* __restrict__ Bt,
    const float* __restrict__ bias, void* __restrict__ Cout,
    uint16_t* __restrict__ vTout, int M, int N, int K) {
  __shared__ __align__(16) uint16_t Alds[128 * 64];
  __shared__ __align__(16) uint16_t Blds[128 * 64];
  const int tid = threadIdx.x;
  const int lane = tid & 63;
  const int w = tid >> 6;
  const int wr = w >> 1, wc = w & 1;
  const int m0 = blockIdx.y * 128, n0 = blockIdx.x * 128;
  const int l15 = lane & 15, l4 = lane >> 4;
  f32x4 acc[4][4] = {};
  for (int k0 = 0; k0 < K; k0 += 64) {
#pragma unroll
    for (int c = 0; c < 4; ++c) {
      int i = c * 256 + tid;
      int row = i >> 3, d = (i & 7) * 8;
      async16(&Alds[i * 8], &A[(size_t)(m0 + row) * K + k0 + d]);
    }
#pragma unroll
    for (int c = 0; c < 4; ++c) {
      int i = c * 256 + tid;
      int row = i >> 3, d = (i & 7) * 8;
      async16(&Blds[i * 8], &Bt[(size_t)(n0 + row) * K + k0 + d]);
    }
    __syncthreads();
#pragma unroll
    for (int kc = 0; kc < 2; ++kc) {
      short8 af[4], bf[4];
#pragma unroll
      for (int m = 0; m < 4; ++m)
        af[m] = *(const short8*)&Alds[(wr * 64 + m * 16 + l15) * 64 + kc * 32 + l4 * 8];
#pragma unroll
      for (int n = 0; n < 4; ++n)
        bf[n] = *(const short8*)&Blds[(wc * 64 + n * 16 + l15) * 64 + kc * 32 + l4 * 8];
#pragma unroll
      for (int m = 0; m < 4; ++m)
#pragma unroll
        for (int n = 0; n < 4; ++n)
          acc[m][n] = __builtin_amdgcn_mfma_f32_16x16x32_bf16(af[m], bf[n], acc[m][n], 0, 0, 0);
    }
    __syncthreads();
  }
#pragma unroll
  for (int m = 0; m < 4; ++m) {
#pragma unroll
    for (int n = 0; n < 4; ++n) {
      int col = n0 + wc * 64 + n * 16 + l15;
      int rowb = m0 + wr * 64 + m * 16 + l4 * 4;
      float bv = bias[col];
      if constexpr (EPI == 3) {
        if (col >= 2048) {
          // V columns -> vT[bh][d][tok], 4 consecutive tokens per lane
          int dtot = col - 2048;
          int hh = dtot >> 6, dd = dtot & 63;
          int bg = rowb >> 11, tl = rowb & 2047;
          ushort4 ov;
          ov.x = f2b(acc[m][n][0] + bv);
          ov.y = f2b(acc[m][n][1] + bv);
          ov.z = f2b(acc[m][n][2] + bv);
          ov.w = f2b(acc[m][n][3] + bv);
          *(ushort4*)&vTout[(((size_t)(bg * 16 + hh)) * 64 + dd) * 2048 + tl] = ov;
          continue;
        }
      }
#pragma unroll
      for (int r = 0; r < 4; ++r) {
        float val = acc[m][n][r] + bv;
        size_t idx = (size_t)(rowb + r) * N + col;
        if constexpr (EPI == 2) {
          float gl = 0.5f * val * (1.0f + erff(val * 0.70710678118654752f));
          ((uint16_t*)Cout)[idx] = f2b(gl);
        } else {
          ((uint16_t*)Cout)[idx] = f2b(val);
        }
      }
    }
  }
}

// ---------------- split-K GEMM: atomicAdd into prefilled f32 out -----------
__global__ __launch_bounds__(256) void k_gemm_splitk(
    const uint16_t* __restrict__ A, const uint16_t* __restrict__ Bt,
    float* __restrict__ out, int M, int N, int K, int Kc) {
  __shared__ __align__(16) uint16_t Alds[128 * 64];
  __shared__ __align__(16) uint16_t Blds[128 * 64];
  const int tid = threadIdx.x;
  const int lane = tid & 63;
  const int w = tid >> 6;
  const int wr = w >> 1, wc = w & 1;
  const int m0 = blockIdx.y * 128, n0 = blockIdx.x * 128;
  const int l15 = lane & 15, l4 = lane >> 4;
  const int kbeg = blockIdx.z * Kc, kend = kbeg + Kc;
  f32x4 acc[4][4] = {};
  for (int k0 = kbeg; k0 < kend; k0 += 64) {
#pragma unroll
    for (int c = 0; c < 4; ++c) {
      int i = c * 256 + tid;
      int row = i >> 3, d = (i & 7) * 8;
      async16(&Alds[i * 8], &A[(size_t)(m0 + row) * K + k0 + d]);
    }
#pragma unroll
    for (int c = 0; c < 4; ++c) {
      int i = c * 256 + tid;
      int row = i >> 3, d = (i & 7) * 8;
      async16(&Blds[i * 8], &Bt[(size_t)(n0 + row) * K + k0 + d]);
    }
    __syncthreads();
#pragma unroll
    for (int kc = 0; kc < 2; ++kc) {
      short8 af[4], bf[4];
#pragma unroll
      for (int m = 0; m < 4; ++m)
        af[m] = *(const short8*)&Alds[(wr * 64 + m * 16 + l15) * 64 + kc * 32 + l4 * 8];
#pragma unroll
      for (int n = 0; n < 4; ++n)
        bf[n] = *(const short8*)&Blds[(wc * 64 + n * 16 + l15) * 64 + kc * 32 + l4 * 8];
#pragma unroll
      for (int m = 0; m < 4; ++m)
#pragma unroll
        for (int n = 0; n < 4; ++n)
          acc[m][n] = __builtin_amdgcn_mfma_f32_16x16x32_bf16(af[m], bf[n], acc[m][n], 0, 0, 0);
    }
    __syncthreads();
  }
#pragma unroll
  for (int m = 0; m < 4; ++m) {
#pragma unroll
    for (int n = 0; n < 4; ++n) {
      int col = n0 + wc * 64 + n * 16 + l15;
      int rowb = m0 + wr * 64 + m * 16 + l4 * 4;
#pragma unroll
      for (int r = 0; r < 4; ++r)
        unsafeAtomicAdd(&out[(size_t)(rowb + r) * N + col], acc[m][n][r]);
    }
  }
}

// ---------------- flash attention v3: swapped QK^T, 32 q/wave, QBLK=128 ----
// S^T = mfma(K_frag, Q_frag): lane=q (l15), regs=16 keys -> in-register
// softmax (15 fmax + 2 shfl). P packed via v_cvt_pk_bf16_f32, ds_write_b64
// into swizzled Plds[32][64]; PV identical layout to before. K/V LDS tiles
// XOR-swizzled (col ^= (row&7)<<3) with pre-swizzled global_load_lds source.
// T13 defer-max: skip O-rescale when __all(pm - m <= 8).
__global__ __launch_bounds__(256) void k_attn(
    const uint16_t* __restrict__ qkv, const uint16_t* __restrict__ vT,
    uint16_t* __restrict__ ctx) {
  __shared__ __align__(16) uint16_t Klds[2][64 * 64];
  __shared__ __align__(16) uint16_t Vlds[2][64 * 64];
  __shared__ __align__(16) uint16_t Plds[4][32 * 64];
  __shared__ __align__(16) float bc[4][2][16];
  const int bh = blockIdx.y, qt = blockIdx.x;
  const int b = bh >> 4, h = bh & 15;
  const int tid = threadIdx.x, lane = tid & 63, w = tid >> 6;
  const int l15 = lane & 15, l4 = lane >> 4;
  const int sw = (l15 & 7) << 3;
  const size_t tokbase = (size_t)b * 2048;

  // Q as B-fragments (col=q=l15, k=d), scaled by 0.125*log2e for exp2 domain
  const float QSC = 0.125f * 1.44269504088896340736f;
  short8 qa[2][2];
#pragma unroll
  for (int g = 0; g < 2; ++g) {
    const int qrow = qt * 128 + w * 32 + g * 16 + l15;
#pragma unroll
    for (int kc = 0; kc < 2; ++kc) {
      short8 v = *(const short8*)&qkv[(tokbase + qrow) * 3072 + h * 64 + kc * 32 + l4 * 8];
#pragma unroll
      for (int j = 0; j < 8; ++j) v[j] = (short)f2b(b2f((uint16_t)v[j]) * QSC);
      qa[g][kc] = v;
    }
  }

  float m_s[2] = {-1e30f, -1e30f}, l_s[2] = {0.f, 0.f};
  f32x4 o[2][4] = {};

  auto stage = [&](int buf, int t0) {
#pragma unroll
    for (int c = 0; c < 2; ++c) {
      int i = c * 256 + tid;
      int row = i >> 3, colE = (i & 7) * 8;
      int colS = colE ^ ((row & 7) << 3);
      async16(&Klds[buf][i * 8],
              &qkv[(tokbase + t0 + row) * 3072 + 1024 + h * 64 + colS]);
    }
#pragma unroll
    for (int c = 0; c < 2; ++c) {
      int i = c * 256 + tid;
      int row = i >> 3, tkE = (i & 7) * 8;
      int tkS = tkE ^ ((row & 7) << 3);
      async16(&Vlds[buf][i * 8],
              &vT[((size_t)bh * 64 + row) * 2048 + t0 + tkS]);
    }
  };

  stage(0, 0);
  __syncthreads();
  int cur = 0;

  for (int t0 = 0; t0 < 2048; t0 += 64) {
    if (t0 + 64 < 2048) stage(cur ^ 1, t0 + 64);

    // S^T = K @ Q^T: one K A-frag feeds both q-groups
    f32x4 s[2][4] = {};
#pragma unroll
    for (int kc = 0; kc < 2; ++kc) {
      const int cc = (kc * 32 + l4 * 8) ^ sw;
#pragma unroll
      for (int c = 0; c < 4; ++c) {
        short8 kf = *(const short8*)&Klds[cur][(c * 16 + l15) * 64 + cc];
        s[0][c] = __builtin_amdgcn_mfma_f32_16x16x32_bf16(kf, qa[0][kc], s[0][c], 0, 0, 0);
        s[1][c] = __builtin_amdgcn_mfma_f32_16x16x32_bf16(kf, qa[1][kc], s[1][c], 0, 0, 0);
      }
    }

    // per-group online softmax: lane owns q-row l15 (16 key-values in regs)
#pragma unroll
    for (int g = 0; g < 2; ++g) {
      float a0 = fmaxf(fmaxf(s[g][0][0], s[g][0][1]), fmaxf(s[g][0][2], s[g][0][3]));
      float a1 = fmaxf(fmaxf(s[g][1][0], s[g][1][1]), fmaxf(s[g][1][2], s[g][1][3]));
      float a2 = fmaxf(fmaxf(s[g][2][0], s[g][2][1]), fmaxf(s[g][2][2], s[g][2][3]));
      float a3 = fmaxf(fmaxf(s[g][3][0], s[g][3][1]), fmaxf(s[g][3][2], s[g][3][3]));
      float pm = fmaxf(fmaxf(a0, a1), fmaxf(a2, a3));
      pm = fmaxf(pm, __shfl_xor(pm, 16));
      pm = fmaxf(pm, __shfl_xor(pm, 32));
      bool noresc = __all(pm - m_s[g] <= 8.f);
      if (!noresc) {
        float mn = fmaxf(m_s[g], pm);
        float scale = exp2f(m_s[g] - mn);
        m_s[g] = mn;
        l_s[g] *= scale;
        if (lane < 16) bc[w][g][lane] = scale;
        f32x4 sc = *(const f32x4*)&bc[w][g][l4 * 4];
#pragma unroll
        for (int df = 0; df < 4; ++df)
#pragma unroll
          for (int r = 0; r < 4; ++r) o[g][df][r] *= sc[r];
      }
      float ps = 0.f;
#pragma unroll
      for (int c = 0; c < 4; ++c) {
        float p0 = exp2f(s[g][c][0] - m_s[g]);
        float p1 = exp2f(s[g][c][1] - m_s[g]);
        float p2 = exp2f(s[g][c][2] - m_s[g]);
        float p3 = exp2f(s[g][c][3] - m_s[g]);
        ps += (p0 + p1) + (p2 + p3);
        uint32_t lo, hi;
        asm("v_cvt_pk_bf16_f32 %0, %1, %2" : "=v"(lo) : "v"(p0), "v"(p1));
        asm("v_cvt_pk_bf16_f32 %0, %1, %2" : "=v"(hi) : "v"(p2), "v"(p3));
        // P[q=g*16+l15][key=c*16+l4*4 .. +3], swizzled, 8B write
        *(uint2*)&Plds[w][(g * 16 + l15) * 64 + ((c * 16 + l4 * 4) ^ sw)] =
            make_uint2(lo, hi);
      }
      ps += __shfl_xor(ps, 16);
      ps += __shfl_xor(ps, 32);
      l_s[g] += ps;
    }

    // O += P @ V (V frags shared across both q-groups)
#pragma unroll
    for (int kc = 0; kc < 2; ++kc) {
      const int cc = (kc * 32 + l4 * 8) ^ sw;
      short8 pa0 = *(const short8*)&Plds[w][l15 * 64 + cc];
      short8 pa1 = *(const short8*)&Plds[w][(16 + l15) * 64 + cc];
#pragma unroll
      for (int df = 0; df < 4; ++df) {
        short8 vf = *(const short8*)&Vlds[cur][(df * 16 + l15) * 64 + cc];
        o[0][df] = __builtin_amdgcn_mfma_f32_16x16x32_bf16(pa0, vf, o[0][df], 0, 0, 0);
        o[1][df] = __builtin_amdgcn_mfma_f32_16x16x32_bf16(pa1, vf, o[1][df], 0, 0, 0);
      }
    }
    __syncthreads();
    cur ^= 1;
  }

  // epilogue: broadcast l across the l4 axis, divide, store
#pragma unroll
  for (int g = 0; g < 2; ++g)
    if (lane < 16) bc[w][g][lane] = l_s[g];
#pragma unroll
  for (int g = 0; g < 2; ++g) {
    f32x4 lv = *(const f32x4*)&bc[w][g][l4 * 4];
#pragma unroll
    for (int r = 0; r < 4; ++r) {
      float rl = 1.0f / lv[r];
      int tok = qt * 128 + w * 32 + g * 16 + l4 * 4 + r;
#pragma unroll
      for (int df = 0; df < 4; ++df) {
        ctx[(tokbase + tok) * 1024 + h * 64 + df * 16 + l15] = f2b(o[g][df][r] * rl);
      }
    }
  }
}

// ---------------------------------------------------------------------------
extern "C" void kernel_launch(void* const* d_in, const int* in_sizes, int n_in,
                              void* d_out, int out_size, void* d_ws, size_t ws_size,
                              hipStream_t stream) {
  const float* x      = (const float*)d_in[0];
  const float* ln1_g  = (const float*)d_in[1];
  const float* ln1_b  = (const float*)d_in[2];
  const float* ln2_g  = (const float*)d_in[3];
  const float* ln2_b  = (const float*)d_in[4];
  const float* w_qkv  = (const float*)d_in[5];
  const float* b_qkv  = (const float*)d_in[6];
  const float* w_proj = (const float*)d_in[7];
  const float* b_proj = (const float*)d_in[8];
  const float* w_fc1  = (const float*)d_in[9];
  const float* b_fc1  = (const float*)d_in[10];
  const float* w_fc2  = (const float*)d_in[11];
  const float* b_fc2  = (const float*)d_in[12];
  float* out = (float*)d_out;
  char* ws = (char*)d_ws;

  // workspace layout (bytes); actb aliases qkvb+vTb (both dead by FC1)
  uint16_t* wTqkv  = (uint16_t*)(ws + 0);         //  6 MB  [3072][1024]
  uint16_t* wTproj = (uint16_t*)(ws + 6291456);   //  2 MB  [1024][1024]
  uint16_t* wTfc1  = (uint16_t*)(ws + 8388608);   //  8 MB  [4096][1024]
  uint16_t* wTfc2  = (uint16_t*)(ws + 16777216);  //  8 MB  [1024][4096]
  uint16_t* hbuf   = (uint16_t*)(ws + 25165824);  //  8 MB  [4096][1024] (h1 then h2)
  uint16_t* qkvb   = (uint16_t*)(ws + 33554432);  // 24 MB  [4096][3072] (V region unused)
  uint16_t* vTb    = (uint16_t*)(ws + 58720256);  //  8 MB  [32][64][2048]
  uint16_t* ctxb   = (uint16_t*)(ws + 67108864);  //  8 MB  [4096][1024]
  float*    x2b    = (float*)   (ws + 75497472);  // 16 MB  [4096][1024]
  uint16_t* actb   = (uint16_t*)(ws + 33554432);  // 32 MB  [4096][4096]

  k_transpose_cast<<<dim3(3072 / 64, 1024 / 64), 256, 0, stream>>>(w_qkv, wTqkv, 1024, 3072);
  k_transpose_cast<<<dim3(1024 / 64, 1024 / 64), 256, 0, stream>>>(w_proj, wTproj, 1024, 1024);
  k_transpose_cast<<<dim3(4096 / 64, 1024 / 64), 256, 0, stream>>>(w_fc1, wTfc1, 1024, 4096);
  k_transpose_cast<<<dim3(1024 / 64, 4096 / 64), 256, 0, stream>>>(w_fc2, wTfc2, 4096, 1024);

  k_layernorm<<<1024, 256, 0, stream>>>(x, ln1_g, ln1_b, hbuf);
  // qkv GEMM: Q/K cols -> qkvb, V cols -> vTb (transposed in-epilogue)
  k_gemm<3><<<dim3(24, 32), 256, 0, stream>>>(hbuf, wTqkv, b_qkv, qkvb, vTb, 4096, 3072, 1024);
  k_attn<<<dim3(16, 32), 256, 0, stream>>>(qkvb, vTb, ctxb);

  // proj: x2 = x + ctx @ w_proj + b_proj   (split-K=2, atomic accumulate)
  k_prefill<<<4096, 256, 0, stream>>>(x, b_proj, x2b, 1024);
  k_gemm_splitk<<<dim3(8, 32, 2), 256, 0, stream>>>(ctxb, wTproj, x2b, 4096, 1024, 1024, 512);

  k_layernorm<<<1024, 256, 0, stream>>>(x2b, ln2_g, ln2_b, hbuf);
  k_gemm<2><<<dim3(32, 32), 256, 0, stream>>>(hbuf, wTfc1, b_fc1, actb, nullptr, 4096, 4096, 1024);

  // fc2: out = x2 + act @ w_fc2 + b_fc2   (split-K=4, atomic accumulate)
  k_prefill<<<4096, 256, 0, stream>>>(x2b, b_fc2, out, 1024);
  k_gemm_splitk<<<dim3(8, 32, 4), 256, 0, stream>>>(actb, wTfc2, out, 4096, 1024, 4096, 1024);
}

// Round 4
// 329.984 us; speedup vs baseline: 1.2784x; 1.1336x over previous
//
#include <hip/hip_runtime.h>
#include <hip/hip_bf16.h>
#include <cstdint>

typedef __attribute__((ext_vector_type(8))) short short8;
typedef __attribute__((ext_vector_type(4))) float f32x4;

__device__ __forceinline__ uint16_t f2b(float f) {
  uint32_t u = __builtin_bit_cast(uint32_t, f);
  return (uint16_t)((u + 0x7FFFu + ((u >> 16) & 1u)) >> 16);
}
__device__ __forceinline__ float b2f(uint16_t h) {
  uint32_t u = ((uint32_t)h) << 16;
  return __builtin_bit_cast(float, u);
}
// async global->LDS, 16B per lane. LDS dest must be wave-uniform base + lane*16.
__device__ __forceinline__ void async16(void* lds, const void* g) {
  __builtin_amdgcn_global_load_lds(
      (const __attribute__((address_space(1))) uint32_t*)g,
      (__attribute__((address_space(3))) uint32_t*)lds, 16, 0, 0);
}
// T1: XCD-chunked bijective remap (nwg % 8 == 0 for all our MFMA grids).
// HW round-robins consecutive ids over 8 XCDs; this gives each XCD a
// contiguous chunk of the logical work order -> A-band/KV-panel L2 reuse.
__device__ __forceinline__ void xcd_remap(int& bx, int& by, int& bz) {
  int gx = gridDim.x, gy = gridDim.y;
  int nwg = gx * gy * gridDim.z;
  int hw = blockIdx.x + gx * (blockIdx.y + gy * blockIdx.z);
  int work = ((nwg & 7) == 0) ? ((hw & 7) * (nwg >> 3) + (hw >> 3)) : hw;
  bx = work % gx;
  int t = work / gx;
  by = t % gy;
  bz = t / gy;
}

// ---------------- weight transpose + cast: w[K][N] f32 -> wT[N][K] bf16 ----
__global__ __launch_bounds__(256) void k_transpose_cast(
    const float* __restrict__ w, uint16_t* __restrict__ wT, int K, int N) {
  __shared__ float tile[64][65];
  const int tx = threadIdx.x;
  const int k0 = blockIdx.y * 64, n0 = blockIdx.x * 64;
  const int cr = tx & 15, rbase = tx >> 4;
#pragma unroll
  for (int rr = 0; rr < 4; ++rr) {
    int k = rbase + rr * 16;
    int n = cr * 4;
    float4 v = *(const float4*)&w[(size_t)(k0 + k) * N + (n0 + n)];
    tile[k][n + 0] = v.x; tile[k][n + 1] = v.y;
    tile[k][n + 2] = v.z; tile[k][n + 3] = v.w;
  }
  __syncthreads();
#pragma unroll
  for (int rr = 0; rr < 4; ++rr) {
    int n = rbase + rr * 16;
    int k = cr * 4;
    ushort4 o;
    o.x = f2b(tile[k + 0][n]);
    o.y = f2b(tile[k + 1][n]);
    o.z = f2b(tile[k + 2][n]);
    o.w = f2b(tile[k + 3][n]);
    *(ushort4*)&wT[(size_t)(n0 + n) * K + (k0 + k)] = o;
  }
}

// ---------------- layernorm: one wave per row of 1024, f32 in -> bf16 out --
__global__ __launch_bounds__(256) void k_layernorm(
    const float* __restrict__ x, const float* __restrict__ g,
    const float* __restrict__ b, uint16_t* __restrict__ out) {
  const int row = blockIdx.x * 4 + (threadIdx.x >> 6);
  const int lane = threadIdx.x & 63;
  const float* xr = x + (size_t)row * 1024;
  float4 v[4];
  float s = 0.f, ss = 0.f;
#pragma unroll
  for (int i = 0; i < 4; ++i) {
    v[i] = *(const float4*)&xr[i * 256 + lane * 4];
    s += v[i].x + v[i].y + v[i].z + v[i].w;
    ss += v[i].x * v[i].x + v[i].y * v[i].y + v[i].z * v[i].z + v[i].w * v[i].w;
  }
#pragma unroll
  for (int off = 1; off < 64; off <<= 1) {
    s += __shfl_xor(s, off);
    ss += __shfl_xor(ss, off);
  }
  float mu = s * (1.f / 1024.f);
  float rstd = rsqrtf(ss * (1.f / 1024.f) - mu * mu + 1e-5f);
#pragma unroll
  for (int i = 0; i < 4; ++i) {
    int col = i * 256 + lane * 4;
    float4 gv = *(const float4*)&g[col];
    float4 bv = *(const float4*)&b[col];
    ushort4 o;
    o.x = f2b((v[i].x - mu) * rstd * gv.x + bv.x);
    o.y = f2b((v[i].y - mu) * rstd * gv.y + bv.y);
    o.z = f2b((v[i].z - mu) * rstd * gv.z + bv.z);
    o.w = f2b((v[i].w - mu) * rstd * gv.w + bv.w);
    *(ushort4*)&out[(size_t)row * 1024 + col] = o;
  }
}

// ---------------- ln2 fuse: x2 = x + bias + pp0 + pp1; h = LN(x2)*g+b ------
__global__ __launch_bounds__(256) void k_ln2_fuse(
    const float* __restrict__ x, const uint16_t* __restrict__ pp0,
    const uint16_t* __restrict__ pp1, const float* __restrict__ bias,
    const float* __restrict__ g, const float* __restrict__ b,
    float* __restrict__ x2, uint16_t* __restrict__ out) {
  const int row = blockIdx.x * 4 + (threadIdx.x >> 6);
  const int lane = threadIdx.x & 63;
  const size_t rb = (size_t)row * 1024;
  float4 v[4];
  float s = 0.f, ss = 0.f;
#pragma unroll
  for (int i = 0; i < 4; ++i) {
    int col = i * 256 + lane * 4;
    float4 xv = *(const float4*)&x[rb + col];
    float4 bv = *(const float4*)&bias[col];
    ushort4 a0 = *(const ushort4*)&pp0[rb + col];
    ushort4 a1 = *(const ushort4*)&pp1[rb + col];
    v[i].x = xv.x + bv.x + b2f(a0.x) + b2f(a1.x);
    v[i].y = xv.y + bv.y + b2f(a0.y) + b2f(a1.y);
    v[i].z = xv.z + bv.z + b2f(a0.z) + b2f(a1.z);
    v[i].w = xv.w + bv.w + b2f(a0.w) + b2f(a1.w);
    *(float4*)&x2[rb + col] = v[i];
    s += v[i].x + v[i].y + v[i].z + v[i].w;
    ss += v[i].x * v[i].x + v[i].y * v[i].y + v[i].z * v[i].z + v[i].w * v[i].w;
  }
#pragma unroll
  for (int off = 1; off < 64; off <<= 1) {
    s += __shfl_xor(s, off);
    ss += __shfl_xor(ss, off);
  }
  float mu = s * (1.f / 1024.f);
  float rstd = rsqrtf(ss * (1.f / 1024.f) - mu * mu + 1e-5f);
#pragma unroll
  for (int i = 0; i < 4; ++i) {
    int col = i * 256 + lane * 4;
    float4 gv = *(const float4*)&g[col];
    float4 bv = *(const float4*)&b[col];
    ushort4 o;
    o.x = f2b((v[i].x - mu) * rstd * gv.x + bv.x);
    o.y = f2b((v[i].y - mu) * rstd * gv.y + bv.y);
    o.z = f2b((v[i].z - mu) * rstd * gv.z + bv.z);
    o.w = f2b((v[i].w - mu) * rstd * gv.w + bv.w);
    *(ushort4*)&out[rb + col] = o;
  }
}

// ---------------- fc2 reduce: out = x2 + bias + fp0+fp1+fp2+fp3 ------------
__global__ __launch_bounds__(256) void k_fc2_reduce(
    const float* __restrict__ x2, const uint16_t* __restrict__ f0,
    const uint16_t* __restrict__ f1, const uint16_t* __restrict__ f2,
    const uint16_t* __restrict__ f3, const float* __restrict__ bias,
    float* __restrict__ out, int N) {
  int i = (blockIdx.x * 256 + threadIdx.x) * 4;
  float4 v = *(const float4*)&x2[i];
  float4 bv = *(const float4*)&bias[i & (N - 1)];
  ushort4 a0 = *(const ushort4*)&f0[i];
  ushort4 a1 = *(const ushort4*)&f1[i];
  ushort4 a2 = *(const ushort4*)&f2[i];
  ushort4 a3 = *(const ushort4*)&f3[i];
  v.x += bv.x + b2f(a0.x) + b2f(a1.x) + b2f(a2.x) + b2f(a3.x);
  v.y += bv.y + b2f(a0.y) + b2f(a1.y) + b2f(a2.y) + b2f(a3.y);
  v.z += bv.z + b2f(a0.z) + b2f(a1.z) + b2f(a2.z) + b2f(a3.z);
  v.w += bv.w + b2f(a0.w) + b2f(a1.w) + b2f(a2.w) + b2f(a3.w);
  *(float4*)&out[i] = v;
}

// ---------------- GEMM: C[M,N] = A[M,K](bf16) @ Bt[N,K](bf16)^T + bias -----
// EPI 0: bf16 out. EPI 2: bf16 out, exact GELU.
// EPI 3: qkv special — cols<2048 -> bf16 C; cols>=2048 (V) -> transposed vT.
template <int EPI>
__global__ __launch_bounds__(256) void k_gemm(
    const uint16_t* __restrict__ A, const uint16_t* __restrict__ Bt,
    const float* __restrict__ bias, void* __restrict__ Cout,
    uint16_t* __restrict__ vTout, int M, int N, int K) {
  __shared__ __align__(16) uint16_t Alds[128 * 64];
  __shared__ __align__(16) uint16_t Blds[128 * 64];
  int bx, by, bz;
  xcd_remap(bx, by, bz);
  const int tid = threadIdx.x;
  const int lane = tid & 63;
  const int w = tid >> 6;
  const int wr = w >> 1, wc = w & 1;
  const int m0 = by * 128, n0 = bx * 128;
  const int l15 = lane & 15, l4 = lane >> 4;
  f32x4 acc[4][4] = {};
  for (int k0 = 0; k0 < K; k0 += 64) {
#pragma unroll
    for (int c = 0; c < 4; ++c) {
      int i = c * 256 + tid;
      int row = i >> 3, d = (i & 7) * 8;
      async16(&Alds[i * 8], &A[(size_t)(m0 + row) * K + k0 + d]);
    }
#pragma unroll
    for (int c = 0; c < 4; ++c) {
      int i = c * 256 + tid;
      int row = i >> 3, d = (i & 7) * 8;
      async16(&Blds[i * 8], &Bt[(size_t)(n0 + row) * K + k0 + d]);
    }
    __syncthreads();
#pragma unroll
    for (int kc = 0; kc < 2; ++kc) {
      short8 af[4], bf[4];
#pragma unroll
      for (int m = 0; m < 4; ++m)
        af[m] = *(const short8*)&Alds[(wr * 64 + m * 16 + l15) * 64 + kc * 32 + l4 * 8];
#pragma unroll
      for (int n = 0; n < 4; ++n)
        bf[n] = *(const short8*)&Blds[(wc * 64 + n * 16 + l15) * 64 + kc * 32 + l4 * 8];
#pragma unroll
      for (int m = 0; m < 4; ++m)
#pragma unroll
        for (int n = 0; n < 4; ++n)
          acc[m][n] = __builtin_amdgcn_mfma_f32_16x16x32_bf16(af[m], bf[n], acc[m][n], 0, 0, 0);
    }
    __syncthreads();
  }
#pragma unroll
  for (int m = 0; m < 4; ++m) {
#pragma unroll
    for (int n = 0; n < 4; ++n) {
      int col = n0 + wc * 64 + n * 16 + l15;
      int rowb = m0 + wr * 64 + m * 16 + l4 * 4;
      float bv = bias[col];
      if constexpr (EPI == 3) {
        if (col >= 2048) {
          // V columns -> vT[bh][d][tok], 4 consecutive tokens per lane
          int dtot = col - 2048;
          int hh = dtot >> 6, dd = dtot & 63;
          int bg = rowb >> 11, tl = rowb & 2047;
          ushort4 ov;
          ov.x = f2b(acc[m][n][0] + bv);
          ov.y = f2b(acc[m][n][1] + bv);
          ov.z = f2b(acc[m][n][2] + bv);
          ov.w = f2b(acc[m][n][3] + bv);
          *(ushort4*)&vTout[(((size_t)(bg * 16 + hh)) * 64 + dd) * 2048 + tl] = ov;
          continue;
        }
      }
#pragma unroll
      for (int r = 0; r < 4; ++r) {
        float val = acc[m][n][r] + bv;
        size_t idx = (size_t)(rowb + r) * N + col;
        if constexpr (EPI == 2) {
          float gl = 0.5f * val * (1.0f + erff(val * 0.70710678118654752f));
          ((uint16_t*)Cout)[idx] = f2b(gl);
        } else {
          ((uint16_t*)Cout)[idx] = f2b(val);
        }
      }
    }
  }
}

// ---------------- split-K GEMM: bf16 partial per k-slice (no atomics) ------
__global__ __launch_bounds__(256) void k_gemm_splitk(
    const uint16_t* __restrict__ A, const uint16_t* __restrict__ Bt,
    uint16_t* __restrict__ p0, uint16_t* __restrict__ p1,
    uint16_t* __restrict__ p2, uint16_t* __restrict__ p3,
    int M, int N, int K, int Kc) {
  __shared__ __align__(16) uint16_t Alds[128 * 64];
  __shared__ __align__(16) uint16_t Blds[128 * 64];
  int bx, by, bz;
  xcd_remap(bx, by, bz);
  const int tid = threadIdx.x;
  const int lane = tid & 63;
  const int w = tid >> 6;
  const int wr = w >> 1, wc = w & 1;
  const int m0 = by * 128, n0 = bx * 128;
  const int l15 = lane & 15, l4 = lane >> 4;
  const int kbeg = bz * Kc, kend = kbeg + Kc;
  uint16_t* __restrict__ P = (bz == 0) ? p0 : (bz == 1) ? p1 : (bz == 2) ? p2 : p3;
  f32x4 acc[4][4] = {};
  for (int k0 = kbeg; k0 < kend; k0 += 64) {
#pragma unroll
    for (int c = 0; c < 4; ++c) {
      int i = c * 256 + tid;
      int row = i >> 3, d = (i & 7) * 8;
      async16(&Alds[i * 8], &A[(size_t)(m0 + row) * K + k0 + d]);
    }
#pragma unroll
    for (int c = 0; c < 4; ++c) {
      int i = c * 256 + tid;
      int row = i >> 3, d = (i & 7) * 8;
      async16(&Blds[i * 8], &Bt[(size_t)(n0 + row) * K + k0 + d]);
    }
    __syncthreads();
#pragma unroll
    for (int kc = 0; kc < 2; ++kc) {
      short8 af[4], bf[4];
#pragma unroll
      for (int m = 0; m < 4; ++m)
        af[m] = *(const short8*)&Alds[(wr * 64 + m * 16 + l15) * 64 + kc * 32 + l4 * 8];
#pragma unroll
      for (int n = 0; n < 4; ++n)
        bf[n] = *(const short8*)&Blds[(wc * 64 + n * 16 + l15) * 64 + kc * 32 + l4 * 8];
#pragma unroll
      for (int m = 0; m < 4; ++m)
#pragma unroll
        for (int n = 0; n < 4; ++n)
          acc[m][n] = __builtin_amdgcn_mfma_f32_16x16x32_bf16(af[m], bf[n], acc[m][n], 0, 0, 0);
    }
    __syncthreads();
  }
#pragma unroll
  for (int m = 0; m < 4; ++m) {
#pragma unroll
    for (int n = 0; n < 4; ++n) {
      int col = n0 + wc * 64 + n * 16 + l15;
      int rowb = m0 + wr * 64 + m * 16 + l4 * 4;
#pragma unroll
      for (int r = 0; r < 4; ++r)
        P[(size_t)(rowb + r) * N + col] = f2b(acc[m][n][r]);
    }
  }
}

// ---------------- flash attention v3: swapped QK^T, 32 q/wave, QBLK=128 ----
__global__ __launch_bounds__(256) void k_attn(
    const uint16_t* __restrict__ qkv, const uint16_t* __restrict__ vT,
    uint16_t* __restrict__ ctx) {
  __shared__ __align__(16) uint16_t Klds[2][64 * 64];
  __shared__ __align__(16) uint16_t Vlds[2][64 * 64];
  __shared__ __align__(16) uint16_t Plds[4][32 * 64];
  __shared__ __align__(16) float bc[4][2][16];
  int bx, by, bz;
  xcd_remap(bx, by, bz);
  const int bh = by, qt = bx;
  const int b = bh >> 4, h = bh & 15;
  const int tid = threadIdx.x, lane = tid & 63, w = tid >> 6;
  const int l15 = lane & 15, l4 = lane >> 4;
  const int sw = (l15 & 7) << 3;
  const size_t tokbase = (size_t)b * 2048;

  // Q as B-fragments (col=q=l15, k=d), scaled by 0.125*log2e for exp2 domain
  const float QSC = 0.125f * 1.44269504088896340736f;
  short8 qa[2][2];
#pragma unroll
  for (int g = 0; g < 2; ++g) {
    const int qrow = qt * 128 + w * 32 + g * 16 + l15;
#pragma unroll
    for (int kc = 0; kc < 2; ++kc) {
      short8 v = *(const short8*)&qkv[(tokbase + qrow) * 3072 + h * 64 + kc * 32 + l4 * 8];
#pragma unroll
      for (int j = 0; j < 8; ++j) v[j] = (short)f2b(b2f((uint16_t)v[j]) * QSC);
      qa[g][kc] = v;
    }
  }

  float m_s[2] = {-1e30f, -1e30f}, l_s[2] = {0.f, 0.f};
  f32x4 o[2][4] = {};

  auto stage = [&](int buf, int t0) {
#pragma unroll
    for (int c = 0; c < 2; ++c) {
      int i = c * 256 + tid;
      int row = i >> 3, colE = (i & 7) * 8;
      int colS = colE ^ ((row & 7) << 3);
      async16(&Klds[buf][i * 8],
              &qkv[(tokbase + t0 + row) * 3072 + 1024 + h * 64 + colS]);
    }
#pragma unroll
    for (int c = 0; c < 2; ++c) {
      int i = c * 256 + tid;
      int row = i >> 3, tkE = (i & 7) * 8;
      int tkS = tkE ^ ((row & 7) << 3);
      async16(&Vlds[buf][i * 8],
              &vT[((size_t)bh * 64 + row) * 2048 + t0 + tkS]);
    }
  };

  stage(0, 0);
  __syncthreads();
  int cur = 0;

  for (int t0 = 0; t0 < 2048; t0 += 64) {
    if (t0 + 64 < 2048) stage(cur ^ 1, t0 + 64);

    // S^T = K @ Q^T: one K A-frag feeds both q-groups
    f32x4 s[2][4] = {};
#pragma unroll
    for (int kc = 0; kc < 2; ++kc) {
      const int cc = (kc * 32 + l4 * 8) ^ sw;
#pragma unroll
      for (int c = 0; c < 4; ++c) {
        short8 kf = *(const short8*)&Klds[cur][(c * 16 + l15) * 64 + cc];
        s[0][c] = __builtin_amdgcn_mfma_f32_16x16x32_bf16(kf, qa[0][kc], s[0][c], 0, 0, 0);
        s[1][c] = __builtin_amdgcn_mfma_f32_16x16x32_bf16(kf, qa[1][kc], s[1][c], 0, 0, 0);
      }
    }

    // per-group online softmax: lane owns q-row l15 (16 key-values in regs)
#pragma unroll
    for (int g = 0; g < 2; ++g) {
      float a0 = fmaxf(fmaxf(s[g][0][0], s[g][0][1]), fmaxf(s[g][0][2], s[g][0][3]));
      float a1 = fmaxf(fmaxf(s[g][1][0], s[g][1][1]), fmaxf(s[g][1][2], s[g][1][3]));
      float a2 = fmaxf(fmaxf(s[g][2][0], s[g][2][1]), fmaxf(s[g][2][2], s[g][2][3]));
      float a3 = fmaxf(fmaxf(s[g][3][0], s[g][3][1]), fmaxf(s[g][3][2], s[g][3][3]));
      float pm = fmaxf(fmaxf(a0, a1), fmaxf(a2, a3));
      pm = fmaxf(pm, __shfl_xor(pm, 16));
      pm = fmaxf(pm, __shfl_xor(pm, 32));
      bool noresc = __all(pm - m_s[g] <= 8.f);
      if (!noresc) {
        float mn = fmaxf(m_s[g], pm);
        float scale = exp2f(m_s[g] - mn);
        m_s[g] = mn;
        l_s[g] *= scale;
        if (lane < 16) bc[w][g][lane] = scale;
        f32x4 sc = *(const f32x4*)&bc[w][g][l4 * 4];
#pragma unroll
        for (int df = 0; df < 4; ++df)
#pragma unroll
          for (int r = 0; r < 4; ++r) o[g][df][r] *= sc[r];
      }
      float ps = 0.f;
#pragma unroll
      for (int c = 0; c < 4; ++c) {
        float p0 = exp2f(s[g][c][0] - m_s[g]);
        float p1 = exp2f(s[g][c][1] - m_s[g]);
        float p2 = exp2f(s[g][c][2] - m_s[g]);
        float p3 = exp2f(s[g][c][3] - m_s[g]);
        ps += (p0 + p1) + (p2 + p3);
        uint32_t lo, hi;
        asm("v_cvt_pk_bf16_f32 %0, %1, %2" : "=v"(lo) : "v"(p0), "v"(p1));
        asm("v_cvt_pk_bf16_f32 %0, %1, %2" : "=v"(hi) : "v"(p2), "v"(p3));
        *(uint2*)&Plds[w][(g * 16 + l15) * 64 + ((c * 16 + l4 * 4) ^ sw)] =
            make_uint2(lo, hi);
      }
      ps += __shfl_xor(ps, 16);
      ps += __shfl_xor(ps, 32);
      l_s[g] += ps;
    }

    // O += P @ V (V frags shared across both q-groups)
#pragma unroll
    for (int kc = 0; kc < 2; ++kc) {
      const int cc = (kc * 32 + l4 * 8) ^ sw;
      short8 pa0 = *(const short8*)&Plds[w][l15 * 64 + cc];
      short8 pa1 = *(const short8*)&Plds[w][(16 + l15) * 64 + cc];
#pragma unroll
      for (int df = 0; df < 4; ++df) {
        short8 vf = *(const short8*)&Vlds[cur][(df * 16 + l15) * 64 + cc];
        o[0][df] = __builtin_amdgcn_mfma_f32_16x16x32_bf16(pa0, vf, o[0][df], 0, 0, 0);
        o[1][df] = __builtin_amdgcn_mfma_f32_16x16x32_bf16(pa1, vf, o[1][df], 0, 0, 0);
      }
    }
    __syncthreads();
    cur ^= 1;
  }

  // epilogue: broadcast l across the l4 axis, divide, store
#pragma unroll
  for (int g = 0; g < 2; ++g)
    if (lane < 16) bc[w][g][lane] = l_s[g];
#pragma unroll
  for (int g = 0; g < 2; ++g) {
    f32x4 lv = *(const f32x4*)&bc[w][g][l4 * 4];
#pragma unroll
    for (int r = 0; r < 4; ++r) {
      float rl = 1.0f / lv[r];
      int tok = qt * 128 + w * 32 + g * 16 + l4 * 4 + r;
#pragma unroll
      for (int df = 0; df < 4; ++df) {
        ctx[(tokbase + tok) * 1024 + h * 64 + df * 16 + l15] = f2b(o[g][df][r] * rl);
      }
    }
  }
}

// ---------------------------------------------------------------------------
extern "C" void kernel_launch(void* const* d_in, const int* in_sizes, int n_in,
                              void* d_out, int out_size, void* d_ws, size_t ws_size,
                              hipStream_t stream) {
  const float* x      = (const float*)d_in[0];
  const float* ln1_g  = (const float*)d_in[1];
  const float* ln1_b  = (const float*)d_in[2];
  const float* ln2_g  = (const float*)d_in[3];
  const float* ln2_b  = (const float*)d_in[4];
  const float* w_qkv  = (const float*)d_in[5];
  const float* b_qkv  = (const float*)d_in[6];
  const float* w_proj = (const float*)d_in[7];
  const float* b_proj = (const float*)d_in[8];
  const float* w_fc1  = (const float*)d_in[9];
  const float* b_fc1  = (const float*)d_in[10];
  const float* w_fc2  = (const float*)d_in[11];
  const float* b_fc2  = (const float*)d_in[12];
  float* out = (float*)d_out;
  char* ws = (char*)d_ws;
  const size_t MB = 1 << 20;

  // workspace layout (MB offsets), peak 88 MB; aliasing by liveness:
  uint16_t* wTfc1  = (uint16_t*)(ws + 0 * MB);    //  8 MB, dead after fc1
  uint16_t* wTfc2  = (uint16_t*)(ws + 8 * MB);    //  8 MB, live to fc2
  uint16_t* wTqkv  = (uint16_t*)(ws + 16 * MB);   //  6 MB, dead after qkv
  uint16_t* wTproj = (uint16_t*)(ws + 22 * MB);   //  2 MB, dead after proj
  uint16_t* hbuf   = (uint16_t*)(ws + 24 * MB);   //  8 MB, dead after fc1
  uint16_t* qkvb   = (uint16_t*)(ws + 32 * MB);   // 24 MB, dead after attn
  uint16_t* vTb    = (uint16_t*)(ws + 56 * MB);   //  8 MB, dead after attn
  uint16_t* ctxb   = (uint16_t*)(ws + 64 * MB);   //  8 MB, dead after proj
  float*    x2b    = (float*)   (ws + 72 * MB);   // 16 MB, live to reduce
  uint16_t* pp0    = (uint16_t*)(ws + 32 * MB);   //  8 MB proj partial (alias qkvb)
  uint16_t* pp1    = (uint16_t*)(ws + 40 * MB);   //  8 MB proj partial
  uint16_t* actb   = (uint16_t*)(ws + 32 * MB);   // 32 MB fc1 out (alias qkvb/vTb)
  uint16_t* fp0    = (uint16_t*)(ws + 16 * MB);   //  8 MB fc2 partial (alias wTqkv/proj)
  uint16_t* fp1    = (uint16_t*)(ws + 24 * MB);   //  8 MB fc2 partial (alias hbuf)
  uint16_t* fp2    = (uint16_t*)(ws + 64 * MB);   //  8 MB fc2 partial (alias ctxb)
  uint16_t* fp3    = (uint16_t*)(ws + 0 * MB);    //  8 MB fc2 partial (alias wTfc1)

  k_transpose_cast<<<dim3(3072 / 64, 1024 / 64), 256, 0, stream>>>(w_qkv, wTqkv, 1024, 3072);
  k_transpose_cast<<<dim3(1024 / 64, 1024 / 64), 256, 0, stream>>>(w_proj, wTproj, 1024, 1024);
  k_transpose_cast<<<dim3(4096 / 64, 1024 / 64), 256, 0, stream>>>(w_fc1, wTfc1, 1024, 4096);
  k_transpose_cast<<<dim3(1024 / 64, 4096 / 64), 256, 0, stream>>>(w_fc2, wTfc2, 4096, 1024);

  k_layernorm<<<1024, 256, 0, stream>>>(x, ln1_g, ln1_b, hbuf);
  // qkv GEMM: Q/K cols -> qkvb, V cols -> vTb (transposed in-epilogue)
  k_gemm<3><<<dim3(24, 32), 256, 0, stream>>>(hbuf, wTqkv, b_qkv, qkvb, vTb, 4096, 3072, 1024);
  k_attn<<<dim3(16, 32), 256, 0, stream>>>(qkvb, vTb, ctxb);

  // proj: partials (split-K=2), reduced inside ln2_fuse
  k_gemm_splitk<<<dim3(8, 32, 2), 256, 0, stream>>>(ctxb, wTproj, pp0, pp1, pp0, pp0,
                                                    4096, 1024, 1024, 512);
  k_ln2_fuse<<<1024, 256, 0, stream>>>(x, pp0, pp1, b_proj, ln2_g, ln2_b, x2b, hbuf);

  k_gemm<2><<<dim3(32, 32), 256, 0, stream>>>(hbuf, wTfc1, b_fc1, actb, nullptr, 4096, 4096, 1024);

  // fc2: partials (split-K=4), reduced with residual+bias into out
  k_gemm_splitk<<<dim3(8, 32, 4), 256, 0, stream>>>(actb, wTfc2, fp0, fp1, fp2, fp3,
                                                    4096, 1024, 4096, 1024);
  k_fc2_reduce<<<4096, 256, 0, stream>>>(x2b, fp0, fp1, fp2, fp3, b_fc2, out, 1024);
}

// Round 5
// 310.107 us; speedup vs baseline: 1.3603x; 1.0641x over previous
//
#include <hip/hip_runtime.h>
#include <hip/hip_bf16.h>
#include <cstdint>

typedef __attribute__((ext_vector_type(8))) short short8;
typedef __attribute__((ext_vector_type(4))) float f32x4;

__device__ __forceinline__ uint16_t f2b(float f) {
  uint32_t u = __builtin_bit_cast(uint32_t, f);
  return (uint16_t)((u + 0x7FFFu + ((u >> 16) & 1u)) >> 16);
}
__device__ __forceinline__ float b2f(uint16_t h) {
  uint32_t u = ((uint32_t)h) << 16;
  return __builtin_bit_cast(float, u);
}
// async global->LDS, 16B per lane. LDS dest must be wave-uniform base + lane*16.
__device__ __forceinline__ void async16(void* lds, const void* g) {
  __builtin_amdgcn_global_load_lds(
      (const __attribute__((address_space(1))) uint32_t*)g,
      (__attribute__((address_space(3))) uint32_t*)lds, 16, 0, 0);
}
// T1: XCD-chunked bijective remap (nwg % 8 == 0 for all our MFMA grids).
__device__ __forceinline__ void xcd_remap(int& bx, int& by, int& bz) {
  int gx = gridDim.x, gy = gridDim.y;
  int nwg = gx * gy * gridDim.z;
  int hw = blockIdx.x + gx * (blockIdx.y + gy * blockIdx.z);
  int work = ((nwg & 7) == 0) ? ((hw & 7) * (nwg >> 3) + (hw >> 3)) : hw;
  bx = work % gx;
  int t = work / gx;
  by = t % gy;
  bz = t / gy;
}

// ---------------- fused weight transpose+cast for all 4 weights ------------
__global__ __launch_bounds__(256) void k_transpose_all(
    const float* __restrict__ wq, const float* __restrict__ wp,
    const float* __restrict__ w1, const float* __restrict__ w2,
    uint16_t* __restrict__ tq, uint16_t* __restrict__ tp,
    uint16_t* __restrict__ t1, uint16_t* __restrict__ t2) {
  __shared__ float tile[64][65];
  int id = blockIdx.x;
  const float* w; uint16_t* wT; int K, N, bx, by;
  if (id < 768)        { w = wq; wT = tq; K = 1024; N = 3072; bx = id % 48; by = id / 48; }
  else if (id < 1024)  { id -= 768;  w = wp; wT = tp; K = 1024; N = 1024; bx = id & 15; by = id >> 4; }
  else if (id < 2048)  { id -= 1024; w = w1; wT = t1; K = 1024; N = 4096; bx = id & 63; by = id >> 6; }
  else                 { id -= 2048; w = w2; wT = t2; K = 4096; N = 1024; bx = id & 15; by = id >> 4; }
  const int tx = threadIdx.x;
  const int k0 = by * 64, n0 = bx * 64;
  const int cr = tx & 15, rbase = tx >> 4;
#pragma unroll
  for (int rr = 0; rr < 4; ++rr) {
    int k = rbase + rr * 16;
    int n = cr * 4;
    float4 v = *(const float4*)&w[(size_t)(k0 + k) * N + (n0 + n)];
    tile[k][n + 0] = v.x; tile[k][n + 1] = v.y;
    tile[k][n + 2] = v.z; tile[k][n + 3] = v.w;
  }
  __syncthreads();
#pragma unroll
  for (int rr = 0; rr < 4; ++rr) {
    int n = rbase + rr * 16;
    int k = cr * 4;
    ushort4 o;
    o.x = f2b(tile[k + 0][n]);
    o.y = f2b(tile[k + 1][n]);
    o.z = f2b(tile[k + 2][n]);
    o.w = f2b(tile[k + 3][n]);
    *(ushort4*)&wT[(size_t)(n0 + n) * K + (k0 + k)] = o;
  }
}

// ---------------- layernorm: one wave per row of 1024, f32 in -> bf16 out --
__global__ __launch_bounds__(256) void k_layernorm(
    const float* __restrict__ x, const float* __restrict__ g,
    const float* __restrict__ b, uint16_t* __restrict__ out) {
  const int row = blockIdx.x * 4 + (threadIdx.x >> 6);
  const int lane = threadIdx.x & 63;
  const float* xr = x + (size_t)row * 1024;
  float4 v[4];
  float s = 0.f, ss = 0.f;
#pragma unroll
  for (int i = 0; i < 4; ++i) {
    v[i] = *(const float4*)&xr[i * 256 + lane * 4];
    s += v[i].x + v[i].y + v[i].z + v[i].w;
    ss += v[i].x * v[i].x + v[i].y * v[i].y + v[i].z * v[i].z + v[i].w * v[i].w;
  }
#pragma unroll
  for (int off = 1; off < 64; off <<= 1) {
    s += __shfl_xor(s, off);
    ss += __shfl_xor(ss, off);
  }
  float mu = s * (1.f / 1024.f);
  float rstd = rsqrtf(ss * (1.f / 1024.f) - mu * mu + 1e-5f);
#pragma unroll
  for (int i = 0; i < 4; ++i) {
    int col = i * 256 + lane * 4;
    float4 gv = *(const float4*)&g[col];
    float4 bv = *(const float4*)&b[col];
    ushort4 o;
    o.x = f2b((v[i].x - mu) * rstd * gv.x + bv.x);
    o.y = f2b((v[i].y - mu) * rstd * gv.y + bv.y);
    o.z = f2b((v[i].z - mu) * rstd * gv.z + bv.z);
    o.w = f2b((v[i].w - mu) * rstd * gv.w + bv.w);
    *(ushort4*)&out[(size_t)row * 1024 + col] = o;
  }
}

// ---------------- ln2 fuse: x2 = x + bias + pp0 + pp1; h = LN(x2)*g+b ------
__global__ __launch_bounds__(256) void k_ln2_fuse(
    const float* __restrict__ x, const uint16_t* __restrict__ pp0,
    const uint16_t* __restrict__ pp1, const float* __restrict__ bias,
    const float* __restrict__ g, const float* __restrict__ b,
    float* __restrict__ x2, uint16_t* __restrict__ out) {
  const int row = blockIdx.x * 4 + (threadIdx.x >> 6);
  const int lane = threadIdx.x & 63;
  const size_t rb = (size_t)row * 1024;
  float4 v[4];
  float s = 0.f, ss = 0.f;
#pragma unroll
  for (int i = 0; i < 4; ++i) {
    int col = i * 256 + lane * 4;
    float4 xv = *(const float4*)&x[rb + col];
    float4 bv = *(const float4*)&bias[col];
    ushort4 a0 = *(const ushort4*)&pp0[rb + col];
    ushort4 a1 = *(const ushort4*)&pp1[rb + col];
    v[i].x = xv.x + bv.x + b2f(a0.x) + b2f(a1.x);
    v[i].y = xv.y + bv.y + b2f(a0.y) + b2f(a1.y);
    v[i].z = xv.z + bv.z + b2f(a0.z) + b2f(a1.z);
    v[i].w = xv.w + bv.w + b2f(a0.w) + b2f(a1.w);
    *(float4*)&x2[rb + col] = v[i];
    s += v[i].x + v[i].y + v[i].z + v[i].w;
    ss += v[i].x * v[i].x + v[i].y * v[i].y + v[i].z * v[i].z + v[i].w * v[i].w;
  }
#pragma unroll
  for (int off = 1; off < 64; off <<= 1) {
    s += __shfl_xor(s, off);
    ss += __shfl_xor(ss, off);
  }
  float mu = s * (1.f / 1024.f);
  float rstd = rsqrtf(ss * (1.f / 1024.f) - mu * mu + 1e-5f);
#pragma unroll
  for (int i = 0; i < 4; ++i) {
    int col = i * 256 + lane * 4;
    float4 gv = *(const float4*)&g[col];
    float4 bv = *(const float4*)&b[col];
    ushort4 o;
    o.x = f2b((v[i].x - mu) * rstd * gv.x + bv.x);
    o.y = f2b((v[i].y - mu) * rstd * gv.y + bv.y);
    o.z = f2b((v[i].z - mu) * rstd * gv.z + bv.z);
    o.w = f2b((v[i].w - mu) * rstd * gv.w + bv.w);
    *(ushort4*)&out[rb + col] = o;
  }
}

// ---------------- fc2 reduce: out = x2 + bias + fp0+fp1+fp2+fp3 ------------
__global__ __launch_bounds__(256) void k_fc2_reduce(
    const float* __restrict__ x2, const uint16_t* __restrict__ f0,
    const uint16_t* __restrict__ f1, const uint16_t* __restrict__ f2,
    const uint16_t* __restrict__ f3, const float* __restrict__ bias,
    float* __restrict__ out, int N) {
  int i = (blockIdx.x * 256 + threadIdx.x) * 4;
  float4 v = *(const float4*)&x2[i];
  float4 bv = *(const float4*)&bias[i & (N - 1)];
  ushort4 a0 = *(const ushort4*)&f0[i];
  ushort4 a1 = *(const ushort4*)&f1[i];
  ushort4 a2 = *(const ushort4*)&f2[i];
  ushort4 a3 = *(const ushort4*)&f3[i];
  v.x += bv.x + b2f(a0.x) + b2f(a1.x) + b2f(a2.x) + b2f(a3.x);
  v.y += bv.y + b2f(a0.y) + b2f(a1.y) + b2f(a2.y) + b2f(a3.y);
  v.z += bv.z + b2f(a0.z) + b2f(a1.z) + b2f(a2.z) + b2f(a3.z);
  v.w += bv.w + b2f(a0.w) + b2f(a1.w) + b2f(a2.w) + b2f(a3.w);
  *(float4*)&out[i] = v;
}

// ---------------- GEMM: C[M,N] = A[M,K](bf16) @ Bt[N,K](bf16)^T + bias -----
// EPI 0: bf16 out. EPI 2: bf16 out, tanh-GELU (max err ~1e-3 vs exact erf).
// EPI 3: qkv special — cols<2048 -> bf16 C; cols>=2048 (V) -> transposed vT.
template <int EPI>
__global__ __launch_bounds__(256) void k_gemm(
    const uint16_t* __restrict__ A, const uint16_t* __restrict__ Bt,
    const float* __restrict__ bias, void* __restrict__ Cout,
    uint16_t* __restrict__ vTout, int M, int N, int K) {
  __shared__ __align__(16) uint16_t Alds[128 * 64];
  __shared__ __align__(16) uint16_t Blds[128 * 64];
  int bx, by, bz;
  xcd_remap(bx, by, bz);
  const int tid = threadIdx.x;
  const int lane = tid & 63;
  const int w = tid >> 6;
  const int wr = w >> 1, wc = w & 1;
  const int m0 = by * 128, n0 = bx * 128;
  const int l15 = lane & 15, l4 = lane >> 4;
  f32x4 acc[4][4] = {};
  for (int k0 = 0; k0 < K; k0 += 64) {
#pragma unroll
    for (int c = 0; c < 4; ++c) {
      int i = c * 256 + tid;
      int row = i >> 3, d = (i & 7) * 8;
      async16(&Alds[i * 8], &A[(size_t)(m0 + row) * K + k0 + d]);
    }
#pragma unroll
    for (int c = 0; c < 4; ++c) {
      int i = c * 256 + tid;
      int row = i >> 3, d = (i & 7) * 8;
      async16(&Blds[i * 8], &Bt[(size_t)(n0 + row) * K + k0 + d]);
    }
    __syncthreads();
#pragma unroll
    for (int kc = 0; kc < 2; ++kc) {
      short8 af[4], bf[4];
#pragma unroll
      for (int m = 0; m < 4; ++m)
        af[m] = *(const short8*)&Alds[(wr * 64 + m * 16 + l15) * 64 + kc * 32 + l4 * 8];
#pragma unroll
      for (int n = 0; n < 4; ++n)
        bf[n] = *(const short8*)&Blds[(wc * 64 + n * 16 + l15) * 64 + kc * 32 + l4 * 8];
#pragma unroll
      for (int m = 0; m < 4; ++m)
#pragma unroll
        for (int n = 0; n < 4; ++n)
          acc[m][n] = __builtin_amdgcn_mfma_f32_16x16x32_bf16(af[m], bf[n], acc[m][n], 0, 0, 0);
    }
    __syncthreads();
  }
#pragma unroll
  for (int m = 0; m < 4; ++m) {
#pragma unroll
    for (int n = 0; n < 4; ++n) {
      int col = n0 + wc * 64 + n * 16 + l15;
      int rowb = m0 + wr * 64 + m * 16 + l4 * 4;
      float bv = bias[col];
      if constexpr (EPI == 3) {
        if (col >= 2048) {
          int dtot = col - 2048;
          int hh = dtot >> 6, dd = dtot & 63;
          int bg = rowb >> 11, tl = rowb & 2047;
          ushort4 ov;
          ov.x = f2b(acc[m][n][0] + bv);
          ov.y = f2b(acc[m][n][1] + bv);
          ov.z = f2b(acc[m][n][2] + bv);
          ov.w = f2b(acc[m][n][3] + bv);
          *(ushort4*)&vTout[(((size_t)(bg * 16 + hh)) * 64 + dd) * 2048 + tl] = ov;
          continue;
        }
      }
#pragma unroll
      for (int r = 0; r < 4; ++r) {
        float val = acc[m][n][r] + bv;
        size_t idx = (size_t)(rowb + r) * N + col;
        if constexpr (EPI == 2) {
          // tanh-form GELU via exp2: gl = val * t/(t+1), t = exp2(2.30221*val*(1+0.044715*val^2))
          float u = val * val;
          float a = fmaf(u, 0.1029480545f, 2.3022078158f);
          float t = exp2f(val * a);
          float gl = val - val / (t + 1.0f);
          ((uint16_t*)Cout)[idx] = f2b(gl);
        } else {
          ((uint16_t*)Cout)[idx] = f2b(val);
        }
      }
    }
  }
}

// ---------------- split-K GEMM: bf16 partial per k-slice (no atomics) ------
__global__ __launch_bounds__(256) void k_gemm_splitk(
    const uint16_t* __restrict__ A, const uint16_t* __restrict__ Bt,
    uint16_t* __restrict__ p0, uint16_t* __restrict__ p1,
    uint16_t* __restrict__ p2, uint16_t* __restrict__ p3,
    int M, int N, int K, int Kc) {
  __shared__ __align__(16) uint16_t Alds[128 * 64];
  __shared__ __align__(16) uint16_t Blds[128 * 64];
  int bx, by, bz;
  xcd_remap(bx, by, bz);
  const int tid = threadIdx.x;
  const int lane = tid & 63;
  const int w = tid >> 6;
  const int wr = w >> 1, wc = w & 1;
  const int m0 = by * 128, n0 = bx * 128;
  const int l15 = lane & 15, l4 = lane >> 4;
  const int kbeg = bz * Kc, kend = kbeg + Kc;
  uint16_t* __restrict__ P = (bz == 0) ? p0 : (bz == 1) ? p1 : (bz == 2) ? p2 : p3;
  f32x4 acc[4][4] = {};
  for (int k0 = kbeg; k0 < kend; k0 += 64) {
#pragma unroll
    for (int c = 0; c < 4; ++c) {
      int i = c * 256 + tid;
      int row = i >> 3, d = (i & 7) * 8;
      async16(&Alds[i * 8], &A[(size_t)(m0 + row) * K + k0 + d]);
    }
#pragma unroll
    for (int c = 0; c < 4; ++c) {
      int i = c * 256 + tid;
      int row = i >> 3, d = (i & 7) * 8;
      async16(&Blds[i * 8], &Bt[(size_t)(n0 + row) * K + k0 + d]);
    }
    __syncthreads();
#pragma unroll
    for (int kc = 0; kc < 2; ++kc) {
      short8 af[4], bf[4];
#pragma unroll
      for (int m = 0; m < 4; ++m)
        af[m] = *(const short8*)&Alds[(wr * 64 + m * 16 + l15) * 64 + kc * 32 + l4 * 8];
#pragma unroll
      for (int n = 0; n < 4; ++n)
        bf[n] = *(const short8*)&Blds[(wc * 64 + n * 16 + l15) * 64 + kc * 32 + l4 * 8];
#pragma unroll
      for (int m = 0; m < 4; ++m)
#pragma unroll
        for (int n = 0; n < 4; ++n)
          acc[m][n] = __builtin_amdgcn_mfma_f32_16x16x32_bf16(af[m], bf[n], acc[m][n], 0, 0, 0);
    }
    __syncthreads();
  }
#pragma unroll
  for (int m = 0; m < 4; ++m) {
#pragma unroll
    for (int n = 0; n < 4; ++n) {
      int col = n0 + wc * 64 + n * 16 + l15;
      int rowb = m0 + wr * 64 + m * 16 + l4 * 4;
#pragma unroll
      for (int r = 0; r < 4; ++r)
        P[(size_t)(rowb + r) * N + col] = f2b(acc[m][n][r]);
    }
  }
}

// ---------------- flash attention v4 ---------------------------------------
// Swapped QK^T (S^T = mfma(K,Q)), 32 q/wave, QBLK=128. Denominator l computed
// by ones-column MFMA (mfma(P, ones) -> D-layout == o's layout: no shuffle
// reduce, no epilogue broadcast). Defer-max (T13) with PER-LANE partial-max
// check (__all spans the wave, so decision is identical); full row-max +
// rescale broadcast only on the rare path. T5 setprio around MFMA clusters.
__global__ __launch_bounds__(256) void k_attn(
    const uint16_t* __restrict__ qkv, const uint16_t* __restrict__ vT,
    uint16_t* __restrict__ ctx) {
  __shared__ __align__(16) uint16_t Klds[2][64 * 64];
  __shared__ __align__(16) uint16_t Vlds[2][64 * 64];
  __shared__ __align__(16) uint16_t Plds[4][32 * 64];
  __shared__ __align__(16) float bc[4][2][16];
  int bx, by, bz;
  xcd_remap(bx, by, bz);
  const int bh = by, qt = bx;
  const int b = bh >> 4, h = bh & 15;
  const int tid = threadIdx.x, lane = tid & 63, w = tid >> 6;
  const int l15 = lane & 15, l4 = lane >> 4;
  const int sw = (l15 & 7) << 3;
  const size_t tokbase = (size_t)b * 2048;

  // Q as B-fragments (col=q=l15, k=d), scaled by 0.125*log2e for exp2 domain
  const float QSC = 0.125f * 1.44269504088896340736f;
  short8 qa[2][2];
#pragma unroll
  for (int g = 0; g < 2; ++g) {
    const int qrow = qt * 128 + w * 32 + g * 16 + l15;
#pragma unroll
    for (int kc = 0; kc < 2; ++kc) {
      short8 v = *(const short8*)&qkv[(tokbase + qrow) * 3072 + h * 64 + kc * 32 + l4 * 8];
#pragma unroll
      for (int j = 0; j < 8; ++j) v[j] = (short)f2b(b2f((uint16_t)v[j]) * QSC);
      qa[g][kc] = v;
    }
  }
  // all-ones bf16 B-fragment for the denominator MFMA
  short8 ones;
#pragma unroll
  for (int j = 0; j < 8; ++j) ones[j] = (short)0x3F80;

  float m_s[2] = {-1e30f, -1e30f};
  f32x4 o[2][4] = {};
  f32x4 ol[2] = {};

  auto stage = [&](int buf, int t0) {
#pragma unroll
    for (int c = 0; c < 2; ++c) {
      int i = c * 256 + tid;
      int row = i >> 3, colE = (i & 7) * 8;
      int colS = colE ^ ((row & 7) << 3);
      async16(&Klds[buf][i * 8],
              &qkv[(tokbase + t0 + row) * 3072 + 1024 + h * 64 + colS]);
    }
#pragma unroll
    for (int c = 0; c < 2; ++c) {
      int i = c * 256 + tid;
      int row = i >> 3, tkE = (i & 7) * 8;
      int tkS = tkE ^ ((row & 7) << 3);
      async16(&Vlds[buf][i * 8],
              &vT[((size_t)bh * 64 + row) * 2048 + t0 + tkS]);
    }
  };

  stage(0, 0);
  __syncthreads();
  int cur = 0;

  for (int t0 = 0; t0 < 2048; t0 += 64) {
    if (t0 + 64 < 2048) stage(cur ^ 1, t0 + 64);

    // S^T = K @ Q^T: one K A-frag feeds both q-groups
    f32x4 s[2][4] = {};
    __builtin_amdgcn_s_setprio(1);
#pragma unroll
    for (int kc = 0; kc < 2; ++kc) {
      const int cc = (kc * 32 + l4 * 8) ^ sw;
#pragma unroll
      for (int c = 0; c < 4; ++c) {
        short8 kf = *(const short8*)&Klds[cur][(c * 16 + l15) * 64 + cc];
        s[0][c] = __builtin_amdgcn_mfma_f32_16x16x32_bf16(kf, qa[0][kc], s[0][c], 0, 0, 0);
        s[1][c] = __builtin_amdgcn_mfma_f32_16x16x32_bf16(kf, qa[1][kc], s[1][c], 0, 0, 0);
      }
    }
    __builtin_amdgcn_s_setprio(0);

    // per-group online softmax: lane owns q-row l15 (16 key-values in regs)
#pragma unroll
    for (int g = 0; g < 2; ++g) {
      float a0 = fmaxf(fmaxf(s[g][0][0], s[g][0][1]), fmaxf(s[g][0][2], s[g][0][3]));
      float a1 = fmaxf(fmaxf(s[g][1][0], s[g][1][1]), fmaxf(s[g][1][2], s[g][1][3]));
      float a2 = fmaxf(fmaxf(s[g][2][0], s[g][2][1]), fmaxf(s[g][2][2], s[g][2][3]));
      float a3 = fmaxf(fmaxf(s[g][3][0], s[g][3][1]), fmaxf(s[g][3][2], s[g][3][3]));
      float pml = fmaxf(fmaxf(a0, a1), fmaxf(a2, a3));  // partial (lane) max
      if (!__all(pml - m_s[g] <= 8.f)) {
        // rare path: true row max, rescale o and ol
        float pm = pml;
        pm = fmaxf(pm, __shfl_xor(pm, 16));
        pm = fmaxf(pm, __shfl_xor(pm, 32));
        float mn = fmaxf(m_s[g], pm);
        float scale = exp2f(m_s[g] - mn);
        m_s[g] = mn;
        if (lane < 16) bc[w][g][lane] = scale;
        f32x4 sc = *(const f32x4*)&bc[w][g][l4 * 4];
#pragma unroll
        for (int df = 0; df < 4; ++df)
#pragma unroll
          for (int r = 0; r < 4; ++r) o[g][df][r] *= sc[r];
#pragma unroll
        for (int r = 0; r < 4; ++r) ol[g][r] *= sc[r];
      }
#pragma unroll
      for (int c = 0; c < 4; ++c) {
        float p0 = exp2f(s[g][c][0] - m_s[g]);
        float p1 = exp2f(s[g][c][1] - m_s[g]);
        float p2 = exp2f(s[g][c][2] - m_s[g]);
        float p3 = exp2f(s[g][c][3] - m_s[g]);
        uint32_t lo, hi;
        asm("v_cvt_pk_bf16_f32 %0, %1, %2" : "=v"(lo) : "v"(p0), "v"(p1));
        asm("v_cvt_pk_bf16_f32 %0, %1, %2" : "=v"(hi) : "v"(p2), "v"(p3));
        *(uint2*)&Plds[w][(g * 16 + l15) * 64 + ((c * 16 + l4 * 4) ^ sw)] =
            make_uint2(lo, hi);
      }
    }

    // O += P @ V; l += P @ ones (same D-layout as O -> no broadcast needed)
    __builtin_amdgcn_s_setprio(1);
#pragma unroll
    for (int kc = 0; kc < 2; ++kc) {
      const int cc = (kc * 32 + l4 * 8) ^ sw;
      short8 pa0 = *(const short8*)&Plds[w][l15 * 64 + cc];
      short8 pa1 = *(const short8*)&Plds[w][(16 + l15) * 64 + cc];
      ol[0] = __builtin_amdgcn_mfma_f32_16x16x32_bf16(pa0, ones, ol[0], 0, 0, 0);
      ol[1] = __builtin_amdgcn_mfma_f32_16x16x32_bf16(pa1, ones, ol[1], 0, 0, 0);
#pragma unroll
      for (int df = 0; df < 4; ++df) {
        short8 vf = *(const short8*)&Vlds[cur][(df * 16 + l15) * 64 + cc];
        o[0][df] = __builtin_amdgcn_mfma_f32_16x16x32_bf16(pa0, vf, o[0][df], 0, 0, 0);
        o[1][df] = __builtin_amdgcn_mfma_f32_16x16x32_bf16(pa1, vf, o[1][df], 0, 0, 0);
      }
    }
    __builtin_amdgcn_s_setprio(0);
    __syncthreads();
    cur ^= 1;
  }

  // epilogue: ol[g][r] is the denominator for q-row l4*4+r (replicated in l15)
#pragma unroll
  for (int g = 0; g < 2; ++g) {
#pragma unroll
    for (int r = 0; r < 4; ++r) {
      float rl = 1.0f / ol[g][r];
      int tok = qt * 128 + w * 32 + g * 16 + l4 * 4 + r;
#pragma unroll
      for (int df = 0; df < 4; ++df) {
        ctx[(tokbase + tok) * 1024 + h * 64 + df * 16 + l15] = f2b(o[g][df][r] * rl);
      }
    }
  }
}

// ---------------------------------------------------------------------------
extern "C" void kernel_launch(void* const* d_in, const int* in_sizes, int n_in,
                              void* d_out, int out_size, void* d_ws, size_t ws_size,
                              hipStream_t stream) {
  const float* x      = (const float*)d_in[0];
  const float* ln1_g  = (const float*)d_in[1];
  const float* ln1_b  = (const float*)d_in[2];
  const float* ln2_g  = (const float*)d_in[3];
  const float* ln2_b  = (const float*)d_in[4];
  const float* w_qkv  = (const float*)d_in[5];
  const float* b_qkv  = (const float*)d_in[6];
  const float* w_proj = (const float*)d_in[7];
  const float* b_proj = (const float*)d_in[8];
  const float* w_fc1  = (const float*)d_in[9];
  const float* b_fc1  = (const float*)d_in[10];
  const float* w_fc2  = (const float*)d_in[11];
  const float* b_fc2  = (const float*)d_in[12];
  float* out = (float*)d_out;
  char* ws = (char*)d_ws;
  const size_t MB = 1 << 20;

  // workspace layout (MB offsets), peak 88 MB; aliasing by liveness:
  uint16_t* wTfc1  = (uint16_t*)(ws + 0 * MB);    //  8 MB, dead after fc1
  uint16_t* wTfc2  = (uint16_t*)(ws + 8 * MB);    //  8 MB, live to fc2
  uint16_t* wTqkv  = (uint16_t*)(ws + 16 * MB);   //  6 MB, dead after qkv
  uint16_t* wTproj = (uint16_t*)(ws + 22 * MB);   //  2 MB, dead after proj
  uint16_t* hbuf   = (uint16_t*)(ws + 24 * MB);   //  8 MB, dead after fc1
  uint16_t* qkvb   = (uint16_t*)(ws + 32 * MB);   // 24 MB, dead after attn
  uint16_t* vTb    = (uint16_t*)(ws + 56 * MB);   //  8 MB, dead after attn
  uint16_t* ctxb   = (uint16_t*)(ws + 64 * MB);   //  8 MB, dead after proj
  float*    x2b    = (float*)   (ws + 72 * MB);   // 16 MB, live to reduce
  uint16_t* pp0    = (uint16_t*)(ws + 32 * MB);   //  8 MB proj partial (alias qkvb)
  uint16_t* pp1    = (uint16_t*)(ws + 40 * MB);   //  8 MB proj partial
  uint16_t* actb   = (uint16_t*)(ws + 32 * MB);   // 32 MB fc1 out (alias qkvb/vTb)
  uint16_t* fp0    = (uint16_t*)(ws + 16 * MB);   //  8 MB fc2 partial (alias wTqkv/proj)
  uint16_t* fp1    = (uint16_t*)(ws + 24 * MB);   //  8 MB fc2 partial (alias hbuf)
  uint16_t* fp2    = (uint16_t*)(ws + 64 * MB);   //  8 MB fc2 partial (alias ctxb)
  uint16_t* fp3    = (uint16_t*)(ws + 0 * MB);    //  8 MB fc2 partial (alias wTfc1)

  k_transpose_all<<<3072, 256, 0, stream>>>(w_qkv, w_proj, w_fc1, w_fc2,
                                            wTqkv, wTproj, wTfc1, wTfc2);

  k_layernorm<<<1024, 256, 0, stream>>>(x, ln1_g, ln1_b, hbuf);
  // qkv GEMM: Q/K cols -> qkvb, V cols -> vTb (transposed in-epilogue)
  k_gemm<3><<<dim3(24, 32), 256, 0, stream>>>(hbuf, wTqkv, b_qkv, qkvb, vTb, 4096, 3072, 1024);
  k_attn<<<dim3(16, 32), 256, 0, stream>>>(qkvb, vTb, ctxb);

  // proj: partials (split-K=2), reduced inside ln2_fuse
  k_gemm_splitk<<<dim3(8, 32, 2), 256, 0, stream>>>(ctxb, wTproj, pp0, pp1, pp0, pp0,
                                                    4096, 1024, 1024, 512);
  k_ln2_fuse<<<1024, 256, 0, stream>>>(x, pp0, pp1, b_proj, ln2_g, ln2_b, x2b, hbuf);

  k_gemm<2><<<dim3(32, 32), 256, 0, stream>>>(hbuf, wTfc1, b_fc1, actb, nullptr, 4096, 4096, 1024);

  // fc2: partials (split-K=4), reduced with residual+bias into out
  k_gemm_splitk<<<dim3(8, 32, 4), 256, 0, stream>>>(actb, wTfc2, fp0, fp1, fp2, fp3,
                                                    4096, 1024, 4096, 1024);
  k_fc2_reduce<<<4096, 256, 0, stream>>>(x2b, fp0, fp1, fp2, fp3, b_fc2, out, 1024);
}